// Round 4
// baseline (4931.828 us; speedup 1.0000x reference)
//
#include <hip/hip_runtime.h>
#include <hip/hip_bf16.h>
#include <hip/hip_fp16.h>

typedef _Float16 f16;
typedef __hip_bfloat16 bf16;
typedef short bf16x8 __attribute__((ext_vector_type(8)));
typedef float f32x4 __attribute__((ext_vector_type(4)));
typedef _Float16 f16x2 __attribute__((ext_vector_type(2)));

#define HDIM 256
#define G4   1024
#define TT   2048
#define NB   64
#define NTOK (64*2048)
#define MPAD 384   // 341 padded to 384 (6 x 64)

// ---------------- helpers ----------------
__device__ __forceinline__ int dot4i(unsigned a, unsigned b, int c) {
#if __has_builtin(__builtin_amdgcn_sdot4)
    return __builtin_amdgcn_sdot4((int)a, (int)b, c, false);
#else
    char4 x = __builtin_bit_cast(char4, a), y = __builtin_bit_cast(char4, b);
    return c + (int)x.x*(int)y.x + (int)x.y*(int)y.y + (int)x.z*(int)y.z + (int)x.w*(int)y.w;
#endif
}

__device__ __forceinline__ float gelu_tanh(float x) {
    // jax.nn.gelu default (approximate=True)
    float x3 = x*x*x;
    float t = tanhf(0.7978845608028654f * (x + 0.044715f * x3));
    return 0.5f * x * (1.0f + t);
}

// ---------------- prep: dtype conversion + padding ----------------
__global__ void k_prep_w(const float* __restrict__ W, bf16* __restrict__ Wb) {
    int i = blockIdx.x*256 + threadIdx.x;          // 262144 total
    Wb[i] = __float2bfloat16(W[i]);
}

// R -> int8 with per-gate-row scale. One wave per row (256 f32 -> 256 i8).
__global__ __launch_bounds__(256) void k_prep_r8(const float* __restrict__ R,
        char* __restrict__ R8, float* __restrict__ rscale) {
    int wave = threadIdx.x >> 6, lane = threadIdx.x & 63;
    int g = blockIdx.x*4 + wave;
    float4 v = ((const float4*)(R + (long)g*256))[lane];
    float mx = fmaxf(fmaxf(fabsf(v.x), fabsf(v.y)), fmaxf(fabsf(v.z), fabsf(v.w)));
    #pragma unroll
    for (int m = 1; m < 64; m <<= 1) mx = fmaxf(mx, __shfl_xor(mx, m, 64));
    float inv = (mx > 0.f) ? 127.f/mx : 0.f;
    int q0 = (int)rintf(v.x*inv), q1 = (int)rintf(v.y*inv);
    int q2 = (int)rintf(v.z*inv), q3 = (int)rintf(v.w*inv);
    unsigned packed = (q0 & 0xff) | ((q1 & 0xff) << 8) | ((q2 & 0xff) << 16) | ((q3 & 0xff) << 24);
    ((unsigned*)(R8 + (long)g*256))[lane] = packed;
    if (lane == 0) rscale[g] = mx * (1.0f/127.f);
}

__global__ void k_prep_gu(const float* __restrict__ gW, const float* __restrict__ uW,
                          const float* __restrict__ gb, const float* __restrict__ ub,
                          bf16* __restrict__ gWb, bf16* __restrict__ uWb,
                          float* __restrict__ gbp, float* __restrict__ ubp) {
    int i = blockIdx.x*256 + threadIdx.x;          // 384*256 total
    int r = i >> 8, c = i & 255;
    gWb[i] = __float2bfloat16(r < 341 ? gW[r*256 + c] : 0.f);
    uWb[i] = __float2bfloat16(r < 341 ? uW[r*256 + c] : 0.f);
    if (i < 384) {
        gbp[i] = i < 341 ? gb[i] : 0.f;
        ubp[i] = i < 341 ? ub[i] : 0.f;
    }
}

__global__ void k_prep_down(const float* __restrict__ dW, bf16* __restrict__ dWb) {
    int i = blockIdx.x*256 + threadIdx.x;          // 256*384 total
    int r = i / 384, c = i % 384;
    dWb[i] = __float2bfloat16(c < 341 ? dW[r*341 + c] : 0.f);
}

// ---------------- LayerNorm 1: f32 -> bf16 ----------------
__global__ __launch_bounds__(256) void k_ln1(const float* __restrict__ x,
        const float* __restrict__ w, const float* __restrict__ b,
        bf16* __restrict__ nx) {
    int wave = threadIdx.x >> 6, lane = threadIdx.x & 63;
    long tok = (long)blockIdx.x * 4 + wave;
    float4 v = ((const float4*)(x + tok*HDIM))[lane];
    float s = v.x + v.y + v.z + v.w;
    float q = v.x*v.x + v.y*v.y + v.z*v.z + v.w*v.w;
    #pragma unroll
    for (int m = 1; m < 64; m <<= 1) { s += __shfl_xor(s, m, 64); q += __shfl_xor(q, m, 64); }
    float mean = s * (1.0f/HDIM);
    float rs = rsqrtf(q*(1.0f/HDIM) - mean*mean + 1e-5f);
    float4 wv = ((const float4*)w)[lane];
    float4 bv = ((const float4*)b)[lane];
    bf16 tmp[4];
    tmp[0] = __float2bfloat16((v.x-mean)*rs*wv.x + bv.x);
    tmp[1] = __float2bfloat16((v.y-mean)*rs*wv.y + bv.y);
    tmp[2] = __float2bfloat16((v.z-mean)*rs*wv.z + bv.z);
    tmp[3] = __float2bfloat16((v.w-mean)*rs*wv.w + bv.w);
    *(ushort4*)(nx + tok*HDIM + lane*4) = *(ushort4*)tmp;
}

// ---------------- LayerNorm 2 + residual: f16 mlp + f32 x -> f32 out ----------------
__global__ __launch_bounds__(256) void k_ln2(const f16* __restrict__ mlp,
        const float* __restrict__ x, const float* __restrict__ w,
        const float* __restrict__ b, float* __restrict__ out) {
    int wave = threadIdx.x >> 6, lane = threadIdx.x & 63;
    long tok = (long)blockIdx.x * 4 + wave;
    const f16* mr = mlp + tok*HDIM + lane*4;
    float4 v; v.x = (float)mr[0]; v.y = (float)mr[1]; v.z = (float)mr[2]; v.w = (float)mr[3];
    float s = v.x + v.y + v.z + v.w;
    float q = v.x*v.x + v.y*v.y + v.z*v.z + v.w*v.w;
    #pragma unroll
    for (int m = 1; m < 64; m <<= 1) { s += __shfl_xor(s, m, 64); q += __shfl_xor(q, m, 64); }
    float mean = s * (1.0f/HDIM);
    float rs = rsqrtf(q*(1.0f/HDIM) - mean*mean + 1e-5f);
    float4 wv = ((const float4*)w)[lane];
    float4 bv = ((const float4*)b)[lane];
    float4 xv = ((const float4*)(x + tok*HDIM))[lane];
    float4 ov;
    ov.x = (v.x-mean)*rs*wv.x + bv.x + xv.x;
    ov.y = (v.y-mean)*rs*wv.y + bv.y + xv.y;
    ov.z = (v.z-mean)*rs*wv.z + bv.z + xv.z;
    ov.w = (v.w-mean)*rs*wv.w + bv.w + xv.w;
    ((float4*)(out + tok*HDIM))[lane] = ov;
}

// ---------------- GEMM: C[M x N] = A[M x K] * B[N x K]^T + bias ----------------
enum { MODE_F16 = 0, MODE_GELU_F16 = 1, MODE_MUL_BF16 = 2 };

template<int MODE>
__global__ __launch_bounds__(256) void k_gemm(
    const bf16* __restrict__ A, const bf16* __restrict__ Bm,
    const float* __restrict__ bias, void* __restrict__ Cv,
    const f16* __restrict__ gatebuf,
    int K, int lda, int ldb, int ldc, int ldg)
{
    // BM=128, BN=64, BK=64; rows stored as 64 bf16 = 128B = 8x16B slots, XOR-swizzled
    __shared__ char Al[128*128];
    __shared__ char Bl[64*128];
    const int tid = threadIdx.x;
    const long bm = (long)blockIdx.x * 128;
    const int bn = blockIdx.y * 64;
    const int wave = tid >> 6, lane = tid & 63;
    const int wm = wave >> 1, wn = wave & 1;        // 2x2 waves, each 64x32
    const int l16 = lane & 15, lq = lane >> 4;
    f32x4 acc[4][2] = {};
    for (int k0 = 0; k0 < K; k0 += 64) {
        #pragma unroll
        for (int p = 0; p < 4; ++p) {               // A: 128 rows x 8 chunks
            int ci = tid + p*256;
            int row = ci >> 3, s = ci & 7;
            uint4 d = *(const uint4*)(A + (bm + row)*lda + k0 + s*8);
            *(uint4*)(Al + row*128 + ((s ^ (row&7))<<4)) = d;
        }
        #pragma unroll
        for (int p = 0; p < 2; ++p) {               // B: 64 rows x 8 chunks
            int ci = tid + p*256;
            int row = ci >> 3, s = ci & 7;
            uint4 d = *(const uint4*)(Bm + (long)(bn + row)*ldb + k0 + s*8);
            *(uint4*)(Bl + row*128 + ((s ^ (row&7))<<4)) = d;
        }
        __syncthreads();
        #pragma unroll
        for (int kc = 0; kc < 2; ++kc) {
            bf16x8 bf[2];
            #pragma unroll
            for (int fn = 0; fn < 2; ++fn) {
                int row = wn*32 + fn*16 + l16;
                int slot = (kc<<2) + lq;
                bf[fn] = *(const bf16x8*)(Bl + row*128 + ((slot ^ (row&7))<<4));
            }
            #pragma unroll
            for (int fm = 0; fm < 4; ++fm) {
                int row = wm*64 + fm*16 + l16;
                int slot = (kc<<2) + lq;
                bf16x8 af = *(const bf16x8*)(Al + row*128 + ((slot ^ (row&7))<<4));
                acc[fm][0] = __builtin_amdgcn_mfma_f32_16x16x32_bf16(af, bf[0], acc[fm][0], 0,0,0);
                acc[fm][1] = __builtin_amdgcn_mfma_f32_16x16x32_bf16(af, bf[1], acc[fm][1], 0,0,0);
            }
        }
        __syncthreads();
    }
    #pragma unroll
    for (int fm = 0; fm < 4; ++fm) {
        #pragma unroll
        for (int fn = 0; fn < 2; ++fn) {
            int n = bn + wn*32 + fn*16 + l16;
            float bv = bias[n];
            #pragma unroll
            for (int r = 0; r < 4; ++r) {
                long m = bm + wm*64 + fm*16 + lq*4 + r;
                float v = acc[fm][fn][r] + bv;
                if constexpr (MODE == MODE_F16) {
                    ((f16*)Cv)[m*ldc + n] = (f16)v;
                } else if constexpr (MODE == MODE_GELU_F16) {
                    ((f16*)Cv)[m*ldc + n] = (f16)gelu_tanh(v);
                } else {
                    float g = (float)gatebuf[m*ldg + n];
                    ((bf16*)Cv)[m*ldc + n] = __float2bfloat16(g * v);
                }
            }
        }
    }
}

// ---------------- sLSTM scan: 64 blocks (1 batch each), 1024 threads ----------------
// i8 path: R8 (per-gate-row scale) fully register-resident; h as two i8 digits
// (hi + lo/254)/127 -> abs err 1.5e-5. Thread layout: kg=tid&3 (k-slice of 64),
// gb=tid>>2 (row j). Thread owns gates {z,i,f,o}[gb] = gb+256m over its k-slice:
// 16 uint4 of R8 in VGPRs. 4 k-partials reduced via 2x shfl_xor (adjacent lanes)
// -> every thread holds all 4 pre-acts for row gb -> fully parallel redundant
// epilogue (4 identical replicas), kg==0 lane publishes h. Ping-pong h_q buffer
// -> ONE barrier per step. waves_per_eu(4,4): 16 waves resident, <=128 VGPR.
__global__ __launch_bounds__(1024) __attribute__((amdgpu_waves_per_eu(4, 4)))
void k_scan(const f16* __restrict__ xW, const char* __restrict__ R8,
            const float* __restrict__ rscale, bf16* __restrict__ h_out)
{
    __shared__ uint4 hq4[128];                       // 2 x 512B: [qhi[256] | qlo[256]]
    char* hq = (char*)hq4;
    const int tid = threadIdx.x;
    const int b   = blockIdx.x;
    const int kg  = tid & 3;                         // k-slice [kg*64, kg*64+64)
    const int gb  = tid >> 2;                        // row j in [0,256)

    // one-time: R8 rows g = gb + 256m, k-slice kg -> 16 uint4 in VGPRs
    uint4 Rr[4][4];
    float rs[4];
    #pragma unroll
    for (int m = 0; m < 4; ++m) {
        const uint4* rp = (const uint4*)(R8 + (long)(gb + 256*m)*256 + kg*64);
        #pragma unroll
        for (int c = 0; c < 4; ++c) Rr[m][c] = rp[c];
        rs[m] = rscale[gb + 256*m];
    }
    if (tid < 128) ((unsigned*)hq)[tid] = 0u;        // zero buffer 0

    float cst = 0.f, nst = 0.f, mst = 0.f;
    const f16* xrow = xW + (long)b * TT * G4 + gb;
    bf16* hrow = h_out + (long)b * TT * HDIM;
    int cur = 0;
    __syncthreads();

    for (int t = 0; t < TT; ++t) {
        float xz = (float)xrow[0];
        float xi = (float)xrow[256];
        float xf = (float)xrow[512];
        float xo = (float)xrow[768];

        const char* hb = hq + cur*512;
        const uint4* hh4 = (const uint4*)(hb + kg*64);
        const uint4* hl4 = (const uint4*)(hb + 256 + kg*64);
        int Shi[4] = {0,0,0,0}, Slo[4] = {0,0,0,0};
        #pragma unroll
        for (int c = 0; c < 4; ++c) {
            uint4 hh = hh4[c];                       // broadcast-ish (4 addrs/wave)
            uint4 hl = hl4[c];
            #pragma unroll
            for (int m = 0; m < 4; ++m) {
                uint4 rv = Rr[m][c];
                Shi[m] = dot4i(rv.x, hh.x, Shi[m]);
                Shi[m] = dot4i(rv.y, hh.y, Shi[m]);
                Shi[m] = dot4i(rv.z, hh.z, Shi[m]);
                Shi[m] = dot4i(rv.w, hh.w, Shi[m]);
                Slo[m] = dot4i(rv.x, hl.x, Slo[m]);
                Slo[m] = dot4i(rv.y, hl.y, Slo[m]);
                Slo[m] = dot4i(rv.z, hl.z, Slo[m]);
                Slo[m] = dot4i(rv.w, hl.w, Slo[m]);
            }
        }
        float p[4];
        #pragma unroll
        for (int m = 0; m < 4; ++m) {
            float v = rs[m] * ((float)Shi[m] * (1.0f/127.0f) + (float)Slo[m] * (1.0f/32258.0f));
            v += __shfl_xor(v, 1, 64);               // reduce 4 k-partials
            v += __shfl_xor(v, 2, 64);               // (adjacent lanes, same wave)
            p[m] = v;
        }
        float pz = p[0] + xz, pi = p[1] + xi, pf = p[2] + xf, po = p[3] + xo;

        // state update: 4 redundant replicas (kg lanes), bitwise identical
        float e = __expf(-2.0f * fabsf(pz));
        float z = copysignf((1.0f - e) / (1.0f + e), pz);
        float o = 1.0f / (1.0f + __expf(-po));
        float mn = fmaxf(pf + mst, pi);
        float ig = __expf(pi - mn);
        float fg = __expf(pf + mst - mn);
        cst = fg*cst + ig*z;
        nst = fg*nst + ig;
        mst = mn;
        float h = o * (cst / nst);

        // publish h into the OTHER buffer (no WAR with this step's reads)
        if (kg == 0) {
            char* hn = hq + (cur^1)*512;
            float eh = h * 127.f;
            int qh = (int)rintf(eh);                 // |h|<1 -> qh in [-127,127]
            int ql = (int)rintf((eh - (float)qh) * 254.f);
            hn[gb] = (char)qh;
            hn[256 + gb] = (char)ql;
            hrow[gb] = __float2bfloat16(h);
        }
        __syncthreads();                             // RAW: h_q ready for t+1
        cur ^= 1;
        xrow += G4;
        hrow += HDIM;
    }
}

// ---------------- launch ----------------
extern "C" void kernel_launch(void* const* d_in, const int* in_sizes, int n_in,
                              void* d_out, int out_size, void* d_ws, size_t ws_size,
                              hipStream_t stream) {
    const float* x     = (const float*)d_in[0];
    const float* ln1w  = (const float*)d_in[1];
    const float* ln1b  = (const float*)d_in[2];
    const float* W     = (const float*)d_in[3];
    const float* R     = (const float*)d_in[4];
    const float* bg    = (const float*)d_in[5];
    const float* upW   = (const float*)d_in[6];
    const float* upb   = (const float*)d_in[7];
    const float* gateW = (const float*)d_in[8];
    const float* gateb = (const float*)d_in[9];
    const float* downW = (const float*)d_in[10];
    const float* downb = (const float*)d_in[11];
    const float* ln2w  = (const float*)d_in[12];
    const float* ln2b  = (const float*)d_in[13];

    char* ws = (char*)d_ws;
    size_t off = 0;
    auto alloc = [&](size_t bytes) { char* p = ws + off; off += (bytes + 255) & ~255ULL; return p; };
    f16*  mlp16   = (f16*)alloc((size_t)NTOK*HDIM*2);     // holds nx first, then mlp (disjoint lifetimes)
    char* regionB = alloc((size_t)NTOK*G4*2);             // xW, then gate_out+prod
    bf16* h       = (bf16*)alloc((size_t)NTOK*HDIM*2);
    bf16* Wb      = (bf16*)alloc(262144*2);
    char* R8      = (char*)alloc(262144);
    float* rscale = (float*)alloc(1024*4);
    bf16* gWb     = (bf16*)alloc((size_t)MPAD*256*2);
    bf16* uWb     = (bf16*)alloc((size_t)MPAD*256*2);
    bf16* dWb     = (bf16*)alloc((size_t)256*MPAD*2);
    float* gbp    = (float*)alloc(MPAD*4);
    float* ubp    = (float*)alloc(MPAD*4);

    bf16* nx       = (bf16*)mlp16;                        // phase 1 use of that region
    f16*  xWb      = (f16*)regionB;                       // 131072 x 1024 f16
    f16*  gate_out = (f16*)regionB;                       // reuse after scan: 131072 x 384 f16
    bf16* prod     = (bf16*)(regionB + (size_t)NTOK*MPAD*2);

    k_prep_w   <<<1024, 256, 0, stream>>>(W, Wb);
    k_prep_r8  <<<256, 256, 0, stream>>>(R, R8, rscale);
    k_prep_gu  <<<384, 256, 0, stream>>>(gateW, upW, gateb, upb, gWb, uWb, gbp, ubp);
    k_prep_down<<<384, 256, 0, stream>>>(downW, dWb);
    k_ln1      <<<NTOK/4, 256, 0, stream>>>(x, ln1w, ln1b, nx);
    // xW = nx @ W^T + b   (f16 out)
    k_gemm<MODE_F16><<<dim3(1024, 16), 256, 0, stream>>>(nx, Wb, bg, xWb, nullptr, 256, 256, 256, 1024, 0);
    // sequential sLSTM scan
    k_scan     <<<64, 1024, 0, stream>>>(xWb, R8, rscale, h);
    // gate = gelu(h @ gateW^T + gate_b)  (f16)
    k_gemm<MODE_GELU_F16><<<dim3(1024, 6), 256, 0, stream>>>(h, gWb, gbp, gate_out, nullptr, 256, 256, 256, MPAD, 0);
    // prod = gate * (h @ upW^T + up_b)   (bf16, padded cols auto-zero)
    k_gemm<MODE_MUL_BF16><<<dim3(1024, 6), 256, 0, stream>>>(h, uWb, ubp, prod, gate_out, 256, 256, 256, MPAD, MPAD);
    // mlp = prod @ downW^T + down_b      (f16 out, K=384)
    k_gemm<MODE_F16><<<dim3(1024, 4), 256, 0, stream>>>(prod, dWb, downb, mlp16, nullptr, MPAD, MPAD, MPAD, HDIM, 0);
    // out = LN(mlp) + x
    k_ln2      <<<NTOK/4, 256, 0, stream>>>(mlp16, x, ln2w, ln2b, (float*)d_out);
}

// Round 5
// 3344.919 us; speedup vs baseline: 1.4744x; 1.4744x over previous
//
#include <hip/hip_runtime.h>
#include <hip/hip_bf16.h>
#include <hip/hip_fp16.h>

typedef _Float16 f16;
typedef __hip_bfloat16 bf16;
typedef short bf16x8 __attribute__((ext_vector_type(8)));
typedef float f32x4 __attribute__((ext_vector_type(4)));
typedef _Float16 f16x2 __attribute__((ext_vector_type(2)));

#define HDIM 256
#define G4   1024
#define TT   2048
#define NB   64
#define NTOK (64*2048)
#define MPAD 384   // 341 padded to 384 (6 x 64)

// ---------------- helpers ----------------
__device__ __forceinline__ int dot4i(unsigned a, unsigned b, int c) {
#if __has_builtin(__builtin_amdgcn_sdot4)
    return __builtin_amdgcn_sdot4((int)a, (int)b, c, false);
#else
    char4 x = __builtin_bit_cast(char4, a), y = __builtin_bit_cast(char4, b);
    return c + (int)x.x*(int)y.x + (int)x.y*(int)y.y + (int)x.z*(int)y.z + (int)x.w*(int)y.w;
#endif
}

__device__ __forceinline__ float gelu_tanh(float x) {
    // jax.nn.gelu default (approximate=True)
    float x3 = x*x*x;
    float t = tanhf(0.7978845608028654f * (x + 0.044715f * x3));
    return 0.5f * x * (1.0f + t);
}

// ---------------- prep: dtype conversion + padding ----------------
__global__ void k_prep_w(const float* __restrict__ W, bf16* __restrict__ Wb) {
    int i = blockIdx.x*256 + threadIdx.x;          // 262144 total
    Wb[i] = __float2bfloat16(W[i]);
}

// R -> int8 with per-gate-row scale. One wave per row (256 f32 -> 256 i8).
__global__ __launch_bounds__(256) void k_prep_r8(const float* __restrict__ R,
        char* __restrict__ R8, float* __restrict__ rscale) {
    int wave = threadIdx.x >> 6, lane = threadIdx.x & 63;
    int g = blockIdx.x*4 + wave;
    float4 v = ((const float4*)(R + (long)g*256))[lane];
    float mx = fmaxf(fmaxf(fabsf(v.x), fabsf(v.y)), fmaxf(fabsf(v.z), fabsf(v.w)));
    #pragma unroll
    for (int m = 1; m < 64; m <<= 1) mx = fmaxf(mx, __shfl_xor(mx, m, 64));
    float inv = (mx > 0.f) ? 127.f/mx : 0.f;
    int q0 = (int)rintf(v.x*inv), q1 = (int)rintf(v.y*inv);
    int q2 = (int)rintf(v.z*inv), q3 = (int)rintf(v.w*inv);
    unsigned packed = (q0 & 0xff) | ((q1 & 0xff) << 8) | ((q2 & 0xff) << 16) | ((q3 & 0xff) << 24);
    ((unsigned*)(R8 + (long)g*256))[lane] = packed;
    if (lane == 0) rscale[g] = mx * (1.0f/127.f);
}

__global__ void k_prep_gu(const float* __restrict__ gW, const float* __restrict__ uW,
                          const float* __restrict__ gb, const float* __restrict__ ub,
                          bf16* __restrict__ gWb, bf16* __restrict__ uWb,
                          float* __restrict__ gbp, float* __restrict__ ubp) {
    int i = blockIdx.x*256 + threadIdx.x;          // 384*256 total
    int r = i >> 8, c = i & 255;
    gWb[i] = __float2bfloat16(r < 341 ? gW[r*256 + c] : 0.f);
    uWb[i] = __float2bfloat16(r < 341 ? uW[r*256 + c] : 0.f);
    if (i < 384) {
        gbp[i] = i < 341 ? gb[i] : 0.f;
        ubp[i] = i < 341 ? ub[i] : 0.f;
    }
}

__global__ void k_prep_down(const float* __restrict__ dW, bf16* __restrict__ dWb) {
    int i = blockIdx.x*256 + threadIdx.x;          // 256*384 total
    int r = i / 384, c = i % 384;
    dWb[i] = __float2bfloat16(c < 341 ? dW[r*341 + c] : 0.f);
}

// ---------------- LayerNorm 1: f32 -> bf16 ----------------
__global__ __launch_bounds__(256) void k_ln1(const float* __restrict__ x,
        const float* __restrict__ w, const float* __restrict__ b,
        bf16* __restrict__ nx) {
    int wave = threadIdx.x >> 6, lane = threadIdx.x & 63;
    long tok = (long)blockIdx.x * 4 + wave;
    float4 v = ((const float4*)(x + tok*HDIM))[lane];
    float s = v.x + v.y + v.z + v.w;
    float q = v.x*v.x + v.y*v.y + v.z*v.z + v.w*v.w;
    #pragma unroll
    for (int m = 1; m < 64; m <<= 1) { s += __shfl_xor(s, m, 64); q += __shfl_xor(q, m, 64); }
    float mean = s * (1.0f/HDIM);
    float rs = rsqrtf(q*(1.0f/HDIM) - mean*mean + 1e-5f);
    float4 wv = ((const float4*)w)[lane];
    float4 bv = ((const float4*)b)[lane];
    bf16 tmp[4];
    tmp[0] = __float2bfloat16((v.x-mean)*rs*wv.x + bv.x);
    tmp[1] = __float2bfloat16((v.y-mean)*rs*wv.y + bv.y);
    tmp[2] = __float2bfloat16((v.z-mean)*rs*wv.z + bv.z);
    tmp[3] = __float2bfloat16((v.w-mean)*rs*wv.w + bv.w);
    *(ushort4*)(nx + tok*HDIM + lane*4) = *(ushort4*)tmp;
}

// ---------------- LayerNorm 2 + residual: f16 mlp + f32 x -> f32 out ----------------
__global__ __launch_bounds__(256) void k_ln2(const f16* __restrict__ mlp,
        const float* __restrict__ x, const float* __restrict__ w,
        const float* __restrict__ b, float* __restrict__ out) {
    int wave = threadIdx.x >> 6, lane = threadIdx.x & 63;
    long tok = (long)blockIdx.x * 4 + wave;
    const f16* mr = mlp + tok*HDIM + lane*4;
    float4 v; v.x = (float)mr[0]; v.y = (float)mr[1]; v.z = (float)mr[2]; v.w = (float)mr[3];
    float s = v.x + v.y + v.z + v.w;
    float q = v.x*v.x + v.y*v.y + v.z*v.z + v.w*v.w;
    #pragma unroll
    for (int m = 1; m < 64; m <<= 1) { s += __shfl_xor(s, m, 64); q += __shfl_xor(q, m, 64); }
    float mean = s * (1.0f/HDIM);
    float rs = rsqrtf(q*(1.0f/HDIM) - mean*mean + 1e-5f);
    float4 wv = ((const float4*)w)[lane];
    float4 bv = ((const float4*)b)[lane];
    float4 xv = ((const float4*)(x + tok*HDIM))[lane];
    float4 ov;
    ov.x = (v.x-mean)*rs*wv.x + bv.x + xv.x;
    ov.y = (v.y-mean)*rs*wv.y + bv.y + xv.y;
    ov.z = (v.z-mean)*rs*wv.z + bv.z + xv.z;
    ov.w = (v.w-mean)*rs*wv.w + bv.w + xv.w;
    ((float4*)(out + tok*HDIM))[lane] = ov;
}

// ---------------- GEMM: C[M x N] = A[M x K] * B[N x K]^T + bias ----------------
// MODE_XW_F16 writes gate-interleaved layout: [m][n&255][n>>8] (4 f16 per row j).
enum { MODE_F16 = 0, MODE_GELU_F16 = 1, MODE_MUL_BF16 = 2, MODE_XW_F16 = 3 };

template<int MODE>
__global__ __launch_bounds__(256) void k_gemm(
    const bf16* __restrict__ A, const bf16* __restrict__ Bm,
    const float* __restrict__ bias, void* __restrict__ Cv,
    const f16* __restrict__ gatebuf,
    int K, int lda, int ldb, int ldc, int ldg)
{
    // BM=128, BN=64, BK=64; rows stored as 64 bf16 = 128B = 8x16B slots, XOR-swizzled
    __shared__ char Al[128*128];
    __shared__ char Bl[64*128];
    const int tid = threadIdx.x;
    const long bm = (long)blockIdx.x * 128;
    const int bn = blockIdx.y * 64;
    const int wave = tid >> 6, lane = tid & 63;
    const int wm = wave >> 1, wn = wave & 1;        // 2x2 waves, each 64x32
    const int l16 = lane & 15, lq = lane >> 4;
    f32x4 acc[4][2] = {};
    for (int k0 = 0; k0 < K; k0 += 64) {
        #pragma unroll
        for (int p = 0; p < 4; ++p) {               // A: 128 rows x 8 chunks
            int ci = tid + p*256;
            int row = ci >> 3, s = ci & 7;
            uint4 d = *(const uint4*)(A + (bm + row)*lda + k0 + s*8);
            *(uint4*)(Al + row*128 + ((s ^ (row&7))<<4)) = d;
        }
        #pragma unroll
        for (int p = 0; p < 2; ++p) {               // B: 64 rows x 8 chunks
            int ci = tid + p*256;
            int row = ci >> 3, s = ci & 7;
            uint4 d = *(const uint4*)(Bm + (long)(bn + row)*ldb + k0 + s*8);
            *(uint4*)(Bl + row*128 + ((s ^ (row&7))<<4)) = d;
        }
        __syncthreads();
        #pragma unroll
        for (int kc = 0; kc < 2; ++kc) {
            bf16x8 bf[2];
            #pragma unroll
            for (int fn = 0; fn < 2; ++fn) {
                int row = wn*32 + fn*16 + l16;
                int slot = (kc<<2) + lq;
                bf[fn] = *(const bf16x8*)(Bl + row*128 + ((slot ^ (row&7))<<4));
            }
            #pragma unroll
            for (int fm = 0; fm < 4; ++fm) {
                int row = wm*64 + fm*16 + l16;
                int slot = (kc<<2) + lq;
                bf16x8 af = *(const bf16x8*)(Al + row*128 + ((slot ^ (row&7))<<4));
                acc[fm][0] = __builtin_amdgcn_mfma_f32_16x16x32_bf16(af, bf[0], acc[fm][0], 0,0,0);
                acc[fm][1] = __builtin_amdgcn_mfma_f32_16x16x32_bf16(af, bf[1], acc[fm][1], 0,0,0);
            }
        }
        __syncthreads();
    }
    #pragma unroll
    for (int fm = 0; fm < 4; ++fm) {
        #pragma unroll
        for (int fn = 0; fn < 2; ++fn) {
            int n = bn + wn*32 + fn*16 + l16;
            float bv = bias[n];
            #pragma unroll
            for (int r = 0; r < 4; ++r) {
                long m = bm + wm*64 + fm*16 + lq*4 + r;
                float v = acc[fm][fn][r] + bv;
                if constexpr (MODE == MODE_F16) {
                    ((f16*)Cv)[m*ldc + n] = (f16)v;
                } else if constexpr (MODE == MODE_XW_F16) {
                    ((f16*)Cv)[m*ldc + ((n & 255) << 2) + (n >> 8)] = (f16)v;
                } else if constexpr (MODE == MODE_GELU_F16) {
                    ((f16*)Cv)[m*ldc + n] = (f16)gelu_tanh(v);
                } else {
                    float g = (float)gatebuf[m*ldg + n];
                    ((bf16*)Cv)[m*ldc + n] = __float2bfloat16(g * v);
                }
            }
        }
    }
}

// ---------------- sLSTM scan: 64 blocks (1 batch each), 1024 threads ----------------
// i8 R (register-resident) x i8 h (single digit, LDS ping-pong). kg=tid&3 owns a
// 64-wide k-slice; gb=tid>>2 owns row j. 4 k-partials reduced by 2x shfl_xor;
// epilogue replicated on the 4 kg lanes (identical), kg==0 publishes h.
// xW staged through LDS in 8-step groups, double-buffered, global load issued
// 2 groups (16 steps, ~7000 cyc) ahead -> no HBM latency on the critical path.
#define PFS 8                                        // steps per prefetch group
#define XBYTES (PFS*2048)                            // 16 KB per group buffer

__global__ __launch_bounds__(1024) __attribute__((amdgpu_waves_per_eu(4, 4)))
void k_scan(const f16* __restrict__ xW, const char* __restrict__ R8,
            const float* __restrict__ rscale, bf16* __restrict__ h_out)
{
    __shared__ char xbuf[2][XBYTES];                 // [buf][step-in-group][row j][4 gates f16]
    __shared__ char hq[2][256];                      // i8 h, ping-pong
    const int tid = threadIdx.x;
    const int b   = blockIdx.x;
    const int kg  = tid & 3;                         // k-slice [kg*64, kg*64+64)
    const int gb  = tid >> 2;                        // row j in [0,256)

    // one-time: R8 rows g = gb + 256m, k-slice kg -> 16 uint4 in VGPRs
    uint4 Rr[4][4];
    float rs[4];
    #pragma unroll
    for (int m = 0; m < 4; ++m) {
        const uint4* rp = (const uint4*)(R8 + (long)(gb + 256*m)*256 + kg*64);
        #pragma unroll
        for (int c = 0; c < 4; ++c) Rr[m][c] = rp[c];
        rs[m] = rscale[gb + 256*m] * (1.0f/127.0f);  // fold h dequant scale
    }
    if (tid < 64) ((unsigned*)hq[0])[tid] = 0u;

    const char* xg = (const char*)(xW + (long)b * TT * G4);  // gate-interleaved rows
    bf16* hrow = h_out + (long)b * TT * HDIM;

    // prefetch pipeline prologue: group 0 -> LDS now, group 1 in flight
    uint4 X = *(const uint4*)(xg + tid*16);
    *(uint4*)(&xbuf[0][tid*16]) = X;                 // waits vmcnt(0) on X
    X = *(const uint4*)(xg + XBYTES + tid*16);
    float cst = 0.f, nst = 0.f, mst = 0.f;
    int cur = 0;
    __syncthreads();

    for (int g = 0; g < TT/PFS; ++g) {
        // X holds group g+1 (arrived ~8 steps ago). Park it, start group g+2.
        if (g+1 < TT/PFS) {
            *(uint4*)(&xbuf[(g+1)&1][tid*16]) = X;
            if (g+2 < TT/PFS)
                X = *(const uint4*)(xg + (long)(g+2)*XBYTES + tid*16);
        }
        const char* xb = xbuf[g&1];
        #pragma unroll
        for (int tt = 0; tt < PFS; ++tt) {
            // 4 gate pre-act biases for row gb: one ds_read_b64
            uint2 xv = *(const uint2*)(xb + tt*2048 + gb*8);
            f16x2 xlo = __builtin_bit_cast(f16x2, xv.x);
            f16x2 xhi = __builtin_bit_cast(f16x2, xv.y);

            const uint4* hh4 = (const uint4*)(hq[cur] + kg*64);
            int S[4] = {0,0,0,0};
            #pragma unroll
            for (int c = 0; c < 4; ++c) {
                uint4 hh = hh4[c];
                #pragma unroll
                for (int m = 0; m < 4; ++m) {
                    uint4 rv = Rr[m][c];
                    S[m] = dot4i(rv.x, hh.x, S[m]);
                    S[m] = dot4i(rv.y, hh.y, S[m]);
                    S[m] = dot4i(rv.z, hh.z, S[m]);
                    S[m] = dot4i(rv.w, hh.w, S[m]);
                }
            }
            float p[4];
            #pragma unroll
            for (int m = 0; m < 4; ++m) {
                float v = rs[m] * (float)S[m];
                v += __shfl_xor(v, 1, 64);           // reduce 4 k-partials
                v += __shfl_xor(v, 2, 64);           // (adjacent lanes, same wave)
                p[m] = v;
            }
            float pz = p[0] + (float)xlo[0];
            float pi = p[1] + (float)xlo[1];
            float pf = p[2] + (float)xhi[0];
            float po = p[3] + (float)xhi[1];

            // state update: 4 redundant replicas (kg lanes), bitwise identical
            float e = __expf(-2.0f * fabsf(pz));
            float z = copysignf((1.0f - e) / (1.0f + e), pz);
            float o = 1.0f / (1.0f + __expf(-po));
            float mn = fmaxf(pf + mst, pi);
            float ig = __expf(pi - mn);
            float fg = __expf(pf + mst - mn);
            cst = fg*cst + ig*z;
            nst = fg*nst + ig;
            mst = mn;
            float h = o * (cst / nst);

            if (kg == 0) {
                hq[cur^1][gb] = (char)(int)rintf(h * 127.f);
                hrow[gb] = __float2bfloat16(h);
            }
            __syncthreads();                         // h ready for next step
            cur ^= 1;
            hrow += HDIM;
        }
    }
}

// ---------------- launch ----------------
extern "C" void kernel_launch(void* const* d_in, const int* in_sizes, int n_in,
                              void* d_out, int out_size, void* d_ws, size_t ws_size,
                              hipStream_t stream) {
    const float* x     = (const float*)d_in[0];
    const float* ln1w  = (const float*)d_in[1];
    const float* ln1b  = (const float*)d_in[2];
    const float* W     = (const float*)d_in[3];
    const float* R     = (const float*)d_in[4];
    const float* bg    = (const float*)d_in[5];
    const float* upW   = (const float*)d_in[6];
    const float* upb   = (const float*)d_in[7];
    const float* gateW = (const float*)d_in[8];
    const float* gateb = (const float*)d_in[9];
    const float* downW = (const float*)d_in[10];
    const float* downb = (const float*)d_in[11];
    const float* ln2w  = (const float*)d_in[12];
    const float* ln2b  = (const float*)d_in[13];

    char* ws = (char*)d_ws;
    size_t off = 0;
    auto alloc = [&](size_t bytes) { char* p = ws + off; off += (bytes + 255) & ~255ULL; return p; };
    f16*  mlp16   = (f16*)alloc((size_t)NTOK*HDIM*2);     // holds nx first, then mlp (disjoint lifetimes)
    char* regionB = alloc((size_t)NTOK*G4*2);             // xW, then gate_out+prod
    bf16* h       = (bf16*)alloc((size_t)NTOK*HDIM*2);
    bf16* Wb      = (bf16*)alloc(262144*2);
    char* R8      = (char*)alloc(262144);
    float* rscale = (float*)alloc(1024*4);
    bf16* gWb     = (bf16*)alloc((size_t)MPAD*256*2);
    bf16* uWb     = (bf16*)alloc((size_t)MPAD*256*2);
    bf16* dWb     = (bf16*)alloc((size_t)256*MPAD*2);
    float* gbp    = (float*)alloc(MPAD*4);
    float* ubp    = (float*)alloc(MPAD*4);

    bf16* nx       = (bf16*)mlp16;                        // phase 1 use of that region
    f16*  xWb      = (f16*)regionB;                       // 131072 x 1024 f16 (gate-interleaved)
    f16*  gate_out = (f16*)regionB;                       // reuse after scan: 131072 x 384 f16
    bf16* prod     = (bf16*)(regionB + (size_t)NTOK*MPAD*2);

    k_prep_w   <<<1024, 256, 0, stream>>>(W, Wb);
    k_prep_r8  <<<256, 256, 0, stream>>>(R, R8, rscale);
    k_prep_gu  <<<384, 256, 0, stream>>>(gateW, upW, gateb, upb, gWb, uWb, gbp, ubp);
    k_prep_down<<<384, 256, 0, stream>>>(downW, dWb);
    k_ln1      <<<NTOK/4, 256, 0, stream>>>(x, ln1w, ln1b, nx);
    // xW = nx @ W^T + b   (f16, gate-interleaved per token)
    k_gemm<MODE_XW_F16><<<dim3(1024, 16), 256, 0, stream>>>(nx, Wb, bg, xWb, nullptr, 256, 256, 256, 1024, 0);
    // sequential sLSTM scan
    k_scan     <<<64, 1024, 0, stream>>>(xWb, R8, rscale, h);
    // gate = gelu(h @ gateW^T + gate_b)  (f16)
    k_gemm<MODE_GELU_F16><<<dim3(1024, 6), 256, 0, stream>>>(h, gWb, gbp, gate_out, nullptr, 256, 256, 256, MPAD, 0);
    // prod = gate * (h @ upW^T + up_b)   (bf16, padded cols auto-zero)
    k_gemm<MODE_MUL_BF16><<<dim3(1024, 6), 256, 0, stream>>>(h, uWb, ubp, prod, gate_out, 256, 256, 256, MPAD, MPAD);
    // mlp = prod @ downW^T + down_b      (f16 out, K=384)
    k_gemm<MODE_F16><<<dim3(1024, 4), 256, 0, stream>>>(prod, dWb, downb, mlp16, nullptr, MPAD, MPAD, MPAD, HDIM, 0);
    // out = LN(mlp) + x
    k_ln2      <<<NTOK/4, 256, 0, stream>>>(mlp16, x, ln2w, ln2b, (float*)d_out);
}

// Round 6
// 3162.022 us; speedup vs baseline: 1.5597x; 1.0578x over previous
//
#include <hip/hip_runtime.h>
#include <hip/hip_bf16.h>
#include <hip/hip_fp16.h>

typedef _Float16 f16;
typedef __hip_bfloat16 bf16;
typedef short bf16x8 __attribute__((ext_vector_type(8)));
typedef float f32x4 __attribute__((ext_vector_type(4)));
typedef _Float16 f16x2 __attribute__((ext_vector_type(2)));

#define HDIM 256
#define G4   1024
#define TT   2048
#define NB   64
#define NTOK (64*2048)
#define MPAD 384   // 341 padded to 384 (6 x 64)

// ---------------- helpers ----------------
__device__ __forceinline__ int dot4i(unsigned a, unsigned b, int c) {
#if __has_builtin(__builtin_amdgcn_sdot4)
    return __builtin_amdgcn_sdot4((int)a, (int)b, c, false);
#else
    char4 x = __builtin_bit_cast(char4, a), y = __builtin_bit_cast(char4, b);
    return c + (int)x.x*(int)y.x + (int)x.y*(int)y.y + (int)x.z*(int)y.z + (int)x.w*(int)y.w;
#endif
}

// reduce across the 4 lanes of a quad (lanes differ in bits 0..1) on the VALU
// pipe: v_add_u32 + quad_perm DPP. xor1 ctrl=0xB1 ([1,0,3,2]), xor2=0x4E ([2,3,0,1]).
__device__ __forceinline__ int quad_red(int v) {
#if __has_builtin(__builtin_amdgcn_update_dpp)
    v += __builtin_amdgcn_update_dpp(0, v, 0xB1, 0xF, 0xF, true);
    v += __builtin_amdgcn_update_dpp(0, v, 0x4E, 0xF, 0xF, true);
    return v;
#else
    v += __shfl_xor(v, 1, 64);
    v += __shfl_xor(v, 2, 64);
    return v;
#endif
}

__device__ __forceinline__ float gelu_tanh(float x) {
    // jax.nn.gelu default (approximate=True)
    float x3 = x*x*x;
    float t = tanhf(0.7978845608028654f * (x + 0.044715f * x3));
    return 0.5f * x * (1.0f + t);
}

// ---------------- prep: dtype conversion + padding ----------------
__global__ void k_prep_w(const float* __restrict__ W, bf16* __restrict__ Wb) {
    int i = blockIdx.x*256 + threadIdx.x;          // 262144 total
    Wb[i] = __float2bfloat16(W[i]);
}

// R -> int8 with per-gate-row scale. One wave per row (256 f32 -> 256 i8).
__global__ __launch_bounds__(256) void k_prep_r8(const float* __restrict__ R,
        char* __restrict__ R8, float* __restrict__ rscale) {
    int wave = threadIdx.x >> 6, lane = threadIdx.x & 63;
    int g = blockIdx.x*4 + wave;
    float4 v = ((const float4*)(R + (long)g*256))[lane];
    float mx = fmaxf(fmaxf(fabsf(v.x), fabsf(v.y)), fmaxf(fabsf(v.z), fabsf(v.w)));
    #pragma unroll
    for (int m = 1; m < 64; m <<= 1) mx = fmaxf(mx, __shfl_xor(mx, m, 64));
    float inv = (mx > 0.f) ? 127.f/mx : 0.f;
    int q0 = (int)rintf(v.x*inv), q1 = (int)rintf(v.y*inv);
    int q2 = (int)rintf(v.z*inv), q3 = (int)rintf(v.w*inv);
    unsigned packed = (q0 & 0xff) | ((q1 & 0xff) << 8) | ((q2 & 0xff) << 16) | ((q3 & 0xff) << 24);
    ((unsigned*)(R8 + (long)g*256))[lane] = packed;
    if (lane == 0) rscale[g] = mx * (1.0f/127.f);
}

__global__ void k_prep_gu(const float* __restrict__ gW, const float* __restrict__ uW,
                          const float* __restrict__ gb, const float* __restrict__ ub,
                          bf16* __restrict__ gWb, bf16* __restrict__ uWb,
                          float* __restrict__ gbp, float* __restrict__ ubp) {
    int i = blockIdx.x*256 + threadIdx.x;          // 384*256 total
    int r = i >> 8, c = i & 255;
    gWb[i] = __float2bfloat16(r < 341 ? gW[r*256 + c] : 0.f);
    uWb[i] = __float2bfloat16(r < 341 ? uW[r*256 + c] : 0.f);
    if (i < 384) {
        gbp[i] = i < 341 ? gb[i] : 0.f;
        ubp[i] = i < 341 ? ub[i] : 0.f;
    }
}

__global__ void k_prep_down(const float* __restrict__ dW, bf16* __restrict__ dWb) {
    int i = blockIdx.x*256 + threadIdx.x;          // 256*384 total
    int r = i / 384, c = i % 384;
    dWb[i] = __float2bfloat16(c < 341 ? dW[r*341 + c] : 0.f);
}

// ---------------- LayerNorm 1: f32 -> bf16 ----------------
__global__ __launch_bounds__(256) void k_ln1(const float* __restrict__ x,
        const float* __restrict__ w, const float* __restrict__ b,
        bf16* __restrict__ nx) {
    int wave = threadIdx.x >> 6, lane = threadIdx.x & 63;
    long tok = (long)blockIdx.x * 4 + wave;
    float4 v = ((const float4*)(x + tok*HDIM))[lane];
    float s = v.x + v.y + v.z + v.w;
    float q = v.x*v.x + v.y*v.y + v.z*v.z + v.w*v.w;
    #pragma unroll
    for (int m = 1; m < 64; m <<= 1) { s += __shfl_xor(s, m, 64); q += __shfl_xor(q, m, 64); }
    float mean = s * (1.0f/HDIM);
    float rs = rsqrtf(q*(1.0f/HDIM) - mean*mean + 1e-5f);
    float4 wv = ((const float4*)w)[lane];
    float4 bv = ((const float4*)b)[lane];
    bf16 tmp[4];
    tmp[0] = __float2bfloat16((v.x-mean)*rs*wv.x + bv.x);
    tmp[1] = __float2bfloat16((v.y-mean)*rs*wv.y + bv.y);
    tmp[2] = __float2bfloat16((v.z-mean)*rs*wv.z + bv.z);
    tmp[3] = __float2bfloat16((v.w-mean)*rs*wv.w + bv.w);
    *(ushort4*)(nx + tok*HDIM + lane*4) = *(ushort4*)tmp;
}

// ---------------- LayerNorm 2 + residual: f16 mlp + f32 x -> f32 out ----------------
__global__ __launch_bounds__(256) void k_ln2(const f16* __restrict__ mlp,
        const float* __restrict__ x, const float* __restrict__ w,
        const float* __restrict__ b, float* __restrict__ out) {
    int wave = threadIdx.x >> 6, lane = threadIdx.x & 63;
    long tok = (long)blockIdx.x * 4 + wave;
    const f16* mr = mlp + tok*HDIM + lane*4;
    float4 v; v.x = (float)mr[0]; v.y = (float)mr[1]; v.z = (float)mr[2]; v.w = (float)mr[3];
    float s = v.x + v.y + v.z + v.w;
    float q = v.x*v.x + v.y*v.y + v.z*v.z + v.w*v.w;
    #pragma unroll
    for (int m = 1; m < 64; m <<= 1) { s += __shfl_xor(s, m, 64); q += __shfl_xor(q, m, 64); }
    float mean = s * (1.0f/HDIM);
    float rs = rsqrtf(q*(1.0f/HDIM) - mean*mean + 1e-5f);
    float4 wv = ((const float4*)w)[lane];
    float4 bv = ((const float4*)b)[lane];
    float4 xv = ((const float4*)(x + tok*HDIM))[lane];
    float4 ov;
    ov.x = (v.x-mean)*rs*wv.x + bv.x + xv.x;
    ov.y = (v.y-mean)*rs*wv.y + bv.y + xv.y;
    ov.z = (v.z-mean)*rs*wv.z + bv.z + xv.z;
    ov.w = (v.w-mean)*rs*wv.w + bv.w + xv.w;
    ((float4*)(out + tok*HDIM))[lane] = ov;
}

// ---------------- GEMM: C[M x N] = A[M x K] * B[N x K]^T + bias ----------------
// MODE_XW_F16 writes gate-interleaved layout: [m][n&255][n>>8] (4 f16 per row j).
enum { MODE_F16 = 0, MODE_GELU_F16 = 1, MODE_MUL_BF16 = 2, MODE_XW_F16 = 3 };

template<int MODE>
__global__ __launch_bounds__(256) void k_gemm(
    const bf16* __restrict__ A, const bf16* __restrict__ Bm,
    const float* __restrict__ bias, void* __restrict__ Cv,
    const f16* __restrict__ gatebuf,
    int K, int lda, int ldb, int ldc, int ldg)
{
    // BM=128, BN=64, BK=64; rows stored as 64 bf16 = 128B = 8x16B slots, XOR-swizzled
    __shared__ char Al[128*128];
    __shared__ char Bl[64*128];
    const int tid = threadIdx.x;
    const long bm = (long)blockIdx.x * 128;
    const int bn = blockIdx.y * 64;
    const int wave = tid >> 6, lane = tid & 63;
    const int wm = wave >> 1, wn = wave & 1;        // 2x2 waves, each 64x32
    const int l16 = lane & 15, lq = lane >> 4;
    f32x4 acc[4][2] = {};
    for (int k0 = 0; k0 < K; k0 += 64) {
        #pragma unroll
        for (int p = 0; p < 4; ++p) {               // A: 128 rows x 8 chunks
            int ci = tid + p*256;
            int row = ci >> 3, s = ci & 7;
            uint4 d = *(const uint4*)(A + (bm + row)*lda + k0 + s*8);
            *(uint4*)(Al + row*128 + ((s ^ (row&7))<<4)) = d;
        }
        #pragma unroll
        for (int p = 0; p < 2; ++p) {               // B: 64 rows x 8 chunks
            int ci = tid + p*256;
            int row = ci >> 3, s = ci & 7;
            uint4 d = *(const uint4*)(Bm + (long)(bn + row)*ldb + k0 + s*8);
            *(uint4*)(Bl + row*128 + ((s ^ (row&7))<<4)) = d;
        }
        __syncthreads();
        #pragma unroll
        for (int kc = 0; kc < 2; ++kc) {
            bf16x8 bf[2];
            #pragma unroll
            for (int fn = 0; fn < 2; ++fn) {
                int row = wn*32 + fn*16 + l16;
                int slot = (kc<<2) + lq;
                bf[fn] = *(const bf16x8*)(Bl + row*128 + ((slot ^ (row&7))<<4));
            }
            #pragma unroll
            for (int fm = 0; fm < 4; ++fm) {
                int row = wm*64 + fm*16 + l16;
                int slot = (kc<<2) + lq;
                bf16x8 af = *(const bf16x8*)(Al + row*128 + ((slot ^ (row&7))<<4));
                acc[fm][0] = __builtin_amdgcn_mfma_f32_16x16x32_bf16(af, bf[0], acc[fm][0], 0,0,0);
                acc[fm][1] = __builtin_amdgcn_mfma_f32_16x16x32_bf16(af, bf[1], acc[fm][1], 0,0,0);
            }
        }
        __syncthreads();
    }
    #pragma unroll
    for (int fm = 0; fm < 4; ++fm) {
        #pragma unroll
        for (int fn = 0; fn < 2; ++fn) {
            int n = bn + wn*32 + fn*16 + l16;
            float bv = bias[n];
            #pragma unroll
            for (int r = 0; r < 4; ++r) {
                long m = bm + wm*64 + fm*16 + lq*4 + r;
                float v = acc[fm][fn][r] + bv;
                if constexpr (MODE == MODE_F16) {
                    ((f16*)Cv)[m*ldc + n] = (f16)v;
                } else if constexpr (MODE == MODE_XW_F16) {
                    ((f16*)Cv)[m*ldc + ((n & 255) << 2) + (n >> 8)] = (f16)v;
                } else if constexpr (MODE == MODE_GELU_F16) {
                    ((f16*)Cv)[m*ldc + n] = (f16)gelu_tanh(v);
                } else {
                    float g = (float)gatebuf[m*ldg + n];
                    ((bf16*)Cv)[m*ldc + n] = __float2bfloat16(g * v);
                }
            }
        }
    }
}

// ---------------- sLSTM scan: 64 blocks (1 batch each), 1024 threads ----------------
// i8 R (fully register-resident) x i8 h (LDS ping-pong, 2x256B — only LDS left).
// kg=tid&3 owns a 64-wide k-slice; gb=tid>>2 owns row j. 4 k-partials reduced on
// the VALU pipe via quad_perm DPP adds (int, exact -> replicas identical).
// x pre-acts: per-thread 8B global loads, software-pipelined 2 steps ahead in two
// NAMED registers XA/XB (even/odd step) — no LDS staging, no runtime reg indexing.
// Epilogue replicated on the 4 kg lanes; kg==0 publishes h. One barrier per step.

#define SCAN_STEP(XREG, TPRE)                                                   \
    do {                                                                        \
        f16x2 xlo = __builtin_bit_cast(f16x2, XREG.x);                          \
        f16x2 xhi = __builtin_bit_cast(f16x2, XREG.y);                          \
        long tp = ((TPRE) < TT) ? (long)(TPRE) : (long)(TT - 1);                \
        XREG = *(const uint2*)(xg + tp*2048);                                   \
        const uint4* hh4 = (const uint4*)(hq[cur] + kg*64);                     \
        int S0 = 0, S1 = 0, S2 = 0, S3 = 0;                                     \
        _Pragma("unroll")                                                       \
        for (int c = 0; c < 4; ++c) {                                           \
            uint4 hh = hh4[c];                                                  \
            uint4 r0 = Rr[0][c], r1 = Rr[1][c], r2 = Rr[2][c], r3 = Rr[3][c];   \
            S0 = dot4i(r0.x, hh.x, S0); S0 = dot4i(r0.y, hh.y, S0);             \
            S0 = dot4i(r0.z, hh.z, S0); S0 = dot4i(r0.w, hh.w, S0);             \
            S1 = dot4i(r1.x, hh.x, S1); S1 = dot4i(r1.y, hh.y, S1);             \
            S1 = dot4i(r1.z, hh.z, S1); S1 = dot4i(r1.w, hh.w, S1);             \
            S2 = dot4i(r2.x, hh.x, S2); S2 = dot4i(r2.y, hh.y, S2);             \
            S2 = dot4i(r2.z, hh.z, S2); S2 = dot4i(r2.w, hh.w, S2);             \
            S3 = dot4i(r3.x, hh.x, S3); S3 = dot4i(r3.y, hh.y, S3);             \
            S3 = dot4i(r3.z, hh.z, S3); S3 = dot4i(r3.w, hh.w, S3);             \
        }                                                                       \
        S0 = quad_red(S0); S1 = quad_red(S1);                                   \
        S2 = quad_red(S2); S3 = quad_red(S3);                                   \
        float pz = rs[0]*(float)S0 + (float)xlo[0];                             \
        float pi = rs[1]*(float)S1 + (float)xlo[1];                             \
        float pf = rs[2]*(float)S2 + (float)xhi[0];                             \
        float po = rs[3]*(float)S3 + (float)xhi[1];                             \
        float e = __expf(-2.0f * fabsf(pz));                                    \
        float z = copysignf((1.0f - e) / (1.0f + e), pz);                       \
        float o = 1.0f / (1.0f + __expf(-po));                                  \
        float mn = fmaxf(pf + mst, pi);                                         \
        float ig = __expf(pi - mn);                                             \
        float fg = __expf(pf + mst - mn);                                       \
        cst = fg*cst + ig*z;                                                    \
        nst = fg*nst + ig;                                                      \
        mst = mn;                                                               \
        float h = o * (cst / nst);                                              \
        if (kg == 0) {                                                          \
            hq[cur^1][gb] = (char)(int)rintf(h * 127.f);                        \
            hrow[gb] = __float2bfloat16(h);                                     \
        }                                                                       \
        __syncthreads();                                                        \
        cur ^= 1;                                                               \
        hrow += HDIM;                                                           \
    } while (0)

__global__ __launch_bounds__(1024) __attribute__((amdgpu_waves_per_eu(4, 4)))
void k_scan(const f16* __restrict__ xW, const char* __restrict__ R8,
            const float* __restrict__ rscale, bf16* __restrict__ h_out)
{
    __shared__ char hq[2][256];                      // i8 h, ping-pong
    const int tid = threadIdx.x;
    const int b   = blockIdx.x;
    const int kg  = tid & 3;                         // k-slice [kg*64, kg*64+64)
    const int gb  = tid >> 2;                        // row j in [0,256)

    // one-time: R8 rows g = gb + 256m, k-slice kg -> 16 uint4 in VGPRs
    uint4 Rr[4][4];
    float rs[4];
    #pragma unroll
    for (int m = 0; m < 4; ++m) {
        const uint4* rp = (const uint4*)(R8 + (long)(gb + 256*m)*256 + kg*64);
        #pragma unroll
        for (int c = 0; c < 4; ++c) Rr[m][c] = rp[c];
        rs[m] = rscale[gb + 256*m] * (1.0f/127.0f);  // fold h dequant scale
    }
    if (tid < 64) ((unsigned*)hq[0])[tid] = 0u;

    const char* xg = (const char*)xW + (long)b * TT * 2048 + gb*8;  // gate-interleaved
    bf16* hrow = h_out + (long)b * TT * HDIM;

    uint2 XA = *(const uint2*)(xg);                  // t = 0
    uint2 XB = *(const uint2*)(xg + 2048);           // t = 1
    float cst = 0.f, nst = 0.f, mst = 0.f;
    int cur = 0;
    __syncthreads();

    for (int t = 0; t < TT; t += 2) {
        SCAN_STEP(XA, t + 2);
        SCAN_STEP(XB, t + 3);
    }
}

// ---------------- launch ----------------
extern "C" void kernel_launch(void* const* d_in, const int* in_sizes, int n_in,
                              void* d_out, int out_size, void* d_ws, size_t ws_size,
                              hipStream_t stream) {
    const float* x     = (const float*)d_in[0];
    const float* ln1w  = (const float*)d_in[1];
    const float* ln1b  = (const float*)d_in[2];
    const float* W     = (const float*)d_in[3];
    const float* R     = (const float*)d_in[4];
    const float* bg    = (const float*)d_in[5];
    const float* upW   = (const float*)d_in[6];
    const float* upb   = (const float*)d_in[7];
    const float* gateW = (const float*)d_in[8];
    const float* gateb = (const float*)d_in[9];
    const float* downW = (const float*)d_in[10];
    const float* downb = (const float*)d_in[11];
    const float* ln2w  = (const float*)d_in[12];
    const float* ln2b  = (const float*)d_in[13];

    char* ws = (char*)d_ws;
    size_t off = 0;
    auto alloc = [&](size_t bytes) { char* p = ws + off; off += (bytes + 255) & ~255ULL; return p; };
    f16*  mlp16   = (f16*)alloc((size_t)NTOK*HDIM*2);     // holds nx first, then mlp (disjoint lifetimes)
    char* regionB = alloc((size_t)NTOK*G4*2);             // xW, then gate_out+prod
    bf16* h       = (bf16*)alloc((size_t)NTOK*HDIM*2);
    bf16* Wb      = (bf16*)alloc(262144*2);
    char* R8      = (char*)alloc(262144);
    float* rscale = (float*)alloc(1024*4);
    bf16* gWb     = (bf16*)alloc((size_t)MPAD*256*2);
    bf16* uWb     = (bf16*)alloc((size_t)MPAD*256*2);
    bf16* dWb     = (bf16*)alloc((size_t)256*MPAD*2);
    float* gbp    = (float*)alloc(MPAD*4);
    float* ubp    = (float*)alloc(MPAD*4);

    bf16* nx       = (bf16*)mlp16;                        // phase 1 use of that region
    f16*  xWb      = (f16*)regionB;                       // 131072 x 1024 f16 (gate-interleaved)
    f16*  gate_out = (f16*)regionB;                       // reuse after scan: 131072 x 384 f16
    bf16* prod     = (bf16*)(regionB + (size_t)NTOK*MPAD*2);

    k_prep_w   <<<1024, 256, 0, stream>>>(W, Wb);
    k_prep_r8  <<<256, 256, 0, stream>>>(R, R8, rscale);
    k_prep_gu  <<<384, 256, 0, stream>>>(gateW, upW, gateb, upb, gWb, uWb, gbp, ubp);
    k_prep_down<<<384, 256, 0, stream>>>(downW, dWb);
    k_ln1      <<<NTOK/4, 256, 0, stream>>>(x, ln1w, ln1b, nx);
    // xW = nx @ W^T + b   (f16, gate-interleaved per token)
    k_gemm<MODE_XW_F16><<<dim3(1024, 16), 256, 0, stream>>>(nx, Wb, bg, xWb, nullptr, 256, 256, 256, 1024, 0);
    // sequential sLSTM scan
    k_scan     <<<64, 1024, 0, stream>>>(xWb, R8, rscale, h);
    // gate = gelu(h @ gateW^T + gate_b)  (f16)
    k_gemm<MODE_GELU_F16><<<dim3(1024, 6), 256, 0, stream>>>(h, gWb, gbp, gate_out, nullptr, 256, 256, 256, MPAD, 0);
    // prod = gate * (h @ upW^T + up_b)   (bf16, padded cols auto-zero)
    k_gemm<MODE_MUL_BF16><<<dim3(1024, 6), 256, 0, stream>>>(h, uWb, ubp, prod, gate_out, 256, 256, 256, MPAD, MPAD);
    // mlp = prod @ downW^T + down_b      (f16 out, K=384)
    k_gemm<MODE_F16><<<dim3(1024, 4), 256, 0, stream>>>(prod, dWb, downb, mlp16, nullptr, MPAD, MPAD, MPAD, HDIM, 0);
    // out = LN(mlp) + x
    k_ln2      <<<NTOK/4, 256, 0, stream>>>(mlp16, x, ln2w, ln2b, (float*)d_out);
}

// Round 7
// 3065.362 us; speedup vs baseline: 1.6089x; 1.0315x over previous
//
#include <hip/hip_runtime.h>
#include <hip/hip_bf16.h>
#include <hip/hip_fp16.h>

typedef _Float16 f16;
typedef __hip_bfloat16 bf16;
typedef short bf16x8 __attribute__((ext_vector_type(8)));
typedef float f32x4 __attribute__((ext_vector_type(4)));
typedef _Float16 f16x2 __attribute__((ext_vector_type(2)));

#define HDIM 256
#define G4   1024
#define TT   2048
#define NB   64
#define NTOK (64*2048)
#define MPAD 384   // 341 padded to 384 (6 x 64)

// ---------------- helpers ----------------
__device__ __forceinline__ int dot4i(unsigned a, unsigned b, int c) {
#if __has_builtin(__builtin_amdgcn_sdot4)
    return __builtin_amdgcn_sdot4((int)a, (int)b, c, false);
#else
    char4 x = __builtin_bit_cast(char4, a), y = __builtin_bit_cast(char4, b);
    return c + (int)x.x*(int)y.x + (int)x.y*(int)y.y + (int)x.z*(int)y.z + (int)x.w*(int)y.w;
#endif
}

// reduce across the 4 lanes of a quad (lanes differ in bits 0..1) on the VALU
// pipe: v_add_u32 + quad_perm DPP. xor1 ctrl=0xB1 ([1,0,3,2]), xor2=0x4E ([2,3,0,1]).
__device__ __forceinline__ int quad_red(int v) {
#if __has_builtin(__builtin_amdgcn_update_dpp)
    v += __builtin_amdgcn_update_dpp(0, v, 0xB1, 0xF, 0xF, true);
    v += __builtin_amdgcn_update_dpp(0, v, 0x4E, 0xF, 0xF, true);
    return v;
#else
    v += __shfl_xor(v, 1, 64);
    v += __shfl_xor(v, 2, 64);
    return v;
#endif
}

__device__ __forceinline__ float gelu_tanh(float x) {
    // jax.nn.gelu default (approximate=True)
    float x3 = x*x*x;
    float t = tanhf(0.7978845608028654f * (x + 0.044715f * x3));
    return 0.5f * x * (1.0f + t);
}

// ---------------- prep: dtype conversion + padding ----------------
__global__ void k_prep_w(const float* __restrict__ W, bf16* __restrict__ Wb) {
    int i = blockIdx.x*256 + threadIdx.x;          // 262144 total
    Wb[i] = __float2bfloat16(W[i]);
}

// R -> int8 with per-gate-row scale. One wave per row (256 f32 -> 256 i8).
__global__ __launch_bounds__(256) void k_prep_r8(const float* __restrict__ R,
        char* __restrict__ R8, float* __restrict__ rscale) {
    int wave = threadIdx.x >> 6, lane = threadIdx.x & 63;
    int g = blockIdx.x*4 + wave;
    float4 v = ((const float4*)(R + (long)g*256))[lane];
    float mx = fmaxf(fmaxf(fabsf(v.x), fabsf(v.y)), fmaxf(fabsf(v.z), fabsf(v.w)));
    #pragma unroll
    for (int m = 1; m < 64; m <<= 1) mx = fmaxf(mx, __shfl_xor(mx, m, 64));
    float inv = (mx > 0.f) ? 127.f/mx : 0.f;
    int q0 = (int)rintf(v.x*inv), q1 = (int)rintf(v.y*inv);
    int q2 = (int)rintf(v.z*inv), q3 = (int)rintf(v.w*inv);
    unsigned packed = (q0 & 0xff) | ((q1 & 0xff) << 8) | ((q2 & 0xff) << 16) | ((q3 & 0xff) << 24);
    ((unsigned*)(R8 + (long)g*256))[lane] = packed;
    if (lane == 0) rscale[g] = mx * (1.0f/127.f);
}

__global__ void k_prep_gu(const float* __restrict__ gW, const float* __restrict__ uW,
                          const float* __restrict__ gb, const float* __restrict__ ub,
                          bf16* __restrict__ gWb, bf16* __restrict__ uWb,
                          float* __restrict__ gbp, float* __restrict__ ubp) {
    int i = blockIdx.x*256 + threadIdx.x;          // 384*256 total
    int r = i >> 8, c = i & 255;
    gWb[i] = __float2bfloat16(r < 341 ? gW[r*256 + c] : 0.f);
    uWb[i] = __float2bfloat16(r < 341 ? uW[r*256 + c] : 0.f);
    if (i < 384) {
        gbp[i] = i < 341 ? gb[i] : 0.f;
        ubp[i] = i < 341 ? ub[i] : 0.f;
    }
}

__global__ void k_prep_down(const float* __restrict__ dW, bf16* __restrict__ dWb) {
    int i = blockIdx.x*256 + threadIdx.x;          // 256*384 total
    int r = i / 384, c = i % 384;
    dWb[i] = __float2bfloat16(c < 341 ? dW[r*341 + c] : 0.f);
}

// ---------------- LayerNorm 1: f32 -> bf16 ----------------
__global__ __launch_bounds__(256) void k_ln1(const float* __restrict__ x,
        const float* __restrict__ w, const float* __restrict__ b,
        bf16* __restrict__ nx) {
    int wave = threadIdx.x >> 6, lane = threadIdx.x & 63;
    long tok = (long)blockIdx.x * 4 + wave;
    float4 v = ((const float4*)(x + tok*HDIM))[lane];
    float s = v.x + v.y + v.z + v.w;
    float q = v.x*v.x + v.y*v.y + v.z*v.z + v.w*v.w;
    #pragma unroll
    for (int m = 1; m < 64; m <<= 1) { s += __shfl_xor(s, m, 64); q += __shfl_xor(q, m, 64); }
    float mean = s * (1.0f/HDIM);
    float rs = rsqrtf(q*(1.0f/HDIM) - mean*mean + 1e-5f);
    float4 wv = ((const float4*)w)[lane];
    float4 bv = ((const float4*)b)[lane];
    bf16 tmp[4];
    tmp[0] = __float2bfloat16((v.x-mean)*rs*wv.x + bv.x);
    tmp[1] = __float2bfloat16((v.y-mean)*rs*wv.y + bv.y);
    tmp[2] = __float2bfloat16((v.z-mean)*rs*wv.z + bv.z);
    tmp[3] = __float2bfloat16((v.w-mean)*rs*wv.w + bv.w);
    *(ushort4*)(nx + tok*HDIM + lane*4) = *(ushort4*)tmp;
}

// ---------------- LayerNorm 2 + residual: f16 mlp + f32 x -> f32 out ----------------
__global__ __launch_bounds__(256) void k_ln2(const f16* __restrict__ mlp,
        const float* __restrict__ x, const float* __restrict__ w,
        const float* __restrict__ b, float* __restrict__ out) {
    int wave = threadIdx.x >> 6, lane = threadIdx.x & 63;
    long tok = (long)blockIdx.x * 4 + wave;
    const f16* mr = mlp + tok*HDIM + lane*4;
    float4 v; v.x = (float)mr[0]; v.y = (float)mr[1]; v.z = (float)mr[2]; v.w = (float)mr[3];
    float s = v.x + v.y + v.z + v.w;
    float q = v.x*v.x + v.y*v.y + v.z*v.z + v.w*v.w;
    #pragma unroll
    for (int m = 1; m < 64; m <<= 1) { s += __shfl_xor(s, m, 64); q += __shfl_xor(q, m, 64); }
    float mean = s * (1.0f/HDIM);
    float rs = rsqrtf(q*(1.0f/HDIM) - mean*mean + 1e-5f);
    float4 wv = ((const float4*)w)[lane];
    float4 bv = ((const float4*)b)[lane];
    float4 xv = ((const float4*)(x + tok*HDIM))[lane];
    float4 ov;
    ov.x = (v.x-mean)*rs*wv.x + bv.x + xv.x;
    ov.y = (v.y-mean)*rs*wv.y + bv.y + xv.y;
    ov.z = (v.z-mean)*rs*wv.z + bv.z + xv.z;
    ov.w = (v.w-mean)*rs*wv.w + bv.w + xv.w;
    ((float4*)(out + tok*HDIM))[lane] = ov;
}

// ---------------- GEMM: C[M x N] = A[M x K] * B[N x K]^T + bias ----------------
// MODE_XW_F16 writes gate-interleaved layout: [m][n&255][n>>8] (4 f16 per row j).
enum { MODE_F16 = 0, MODE_GELU_F16 = 1, MODE_MUL_BF16 = 2, MODE_XW_F16 = 3 };

template<int MODE>
__global__ __launch_bounds__(256) void k_gemm(
    const bf16* __restrict__ A, const bf16* __restrict__ Bm,
    const float* __restrict__ bias, void* __restrict__ Cv,
    const f16* __restrict__ gatebuf,
    int K, int lda, int ldb, int ldc, int ldg)
{
    // BM=128, BN=64, BK=64; rows stored as 64 bf16 = 128B = 8x16B slots, XOR-swizzled
    __shared__ char Al[128*128];
    __shared__ char Bl[64*128];
    const int tid = threadIdx.x;
    const long bm = (long)blockIdx.x * 128;
    const int bn = blockIdx.y * 64;
    const int wave = tid >> 6, lane = tid & 63;
    const int wm = wave >> 1, wn = wave & 1;        // 2x2 waves, each 64x32
    const int l16 = lane & 15, lq = lane >> 4;
    f32x4 acc[4][2] = {};
    for (int k0 = 0; k0 < K; k0 += 64) {
        #pragma unroll
        for (int p = 0; p < 4; ++p) {               // A: 128 rows x 8 chunks
            int ci = tid + p*256;
            int row = ci >> 3, s = ci & 7;
            uint4 d = *(const uint4*)(A + (bm + row)*lda + k0 + s*8);
            *(uint4*)(Al + row*128 + ((s ^ (row&7))<<4)) = d;
        }
        #pragma unroll
        for (int p = 0; p < 2; ++p) {               // B: 64 rows x 8 chunks
            int ci = tid + p*256;
            int row = ci >> 3, s = ci & 7;
            uint4 d = *(const uint4*)(Bm + (long)(bn + row)*ldb + k0 + s*8);
            *(uint4*)(Bl + row*128 + ((s ^ (row&7))<<4)) = d;
        }
        __syncthreads();
        #pragma unroll
        for (int kc = 0; kc < 2; ++kc) {
            bf16x8 bf[2];
            #pragma unroll
            for (int fn = 0; fn < 2; ++fn) {
                int row = wn*32 + fn*16 + l16;
                int slot = (kc<<2) + lq;
                bf[fn] = *(const bf16x8*)(Bl + row*128 + ((slot ^ (row&7))<<4));
            }
            #pragma unroll
            for (int fm = 0; fm < 4; ++fm) {
                int row = wm*64 + fm*16 + l16;
                int slot = (kc<<2) + lq;
                bf16x8 af = *(const bf16x8*)(Al + row*128 + ((slot ^ (row&7))<<4));
                acc[fm][0] = __builtin_amdgcn_mfma_f32_16x16x32_bf16(af, bf[0], acc[fm][0], 0,0,0);
                acc[fm][1] = __builtin_amdgcn_mfma_f32_16x16x32_bf16(af, bf[1], acc[fm][1], 0,0,0);
            }
        }
        __syncthreads();
    }
    #pragma unroll
    for (int fm = 0; fm < 4; ++fm) {
        #pragma unroll
        for (int fn = 0; fn < 2; ++fn) {
            int n = bn + wn*32 + fn*16 + l16;
            float bv = bias[n];
            #pragma unroll
            for (int r = 0; r < 4; ++r) {
                long m = bm + wm*64 + fm*16 + lq*4 + r;
                float v = acc[fm][fn][r] + bv;
                if constexpr (MODE == MODE_F16) {
                    ((f16*)Cv)[m*ldc + n] = (f16)v;
                } else if constexpr (MODE == MODE_XW_F16) {
                    ((f16*)Cv)[m*ldc + ((n & 255) << 2) + (n >> 8)] = (f16)v;
                } else if constexpr (MODE == MODE_GELU_F16) {
                    ((f16*)Cv)[m*ldc + n] = (f16)gelu_tanh(v);
                } else {
                    float g = (float)gatebuf[m*ldg + n];
                    ((bf16*)Cv)[m*ldc + n] = __float2bfloat16(g * v);
                }
            }
        }
    }
}

// ---------------- sLSTM scan: 64 blocks (1 batch each), 1024 threads ----------------
// i8 R (fully register-resident) x i8 h (LDS ping-pong, 2x256B). kg=tid&3 owns a
// 64-wide k-slice; gb=tid>>2 owns row j. Quad DPP reduce; x pre-acts in two named
// regs (XA/XB) prefetched 2 steps ahead.
// KEY (this round): the per-step barrier is a RAW s_barrier with lgkmcnt(0) only.
// __syncthreads() would drain vmcnt(0) every step (waiting the in-flight x
// prefetch AND the h store), serializing ~500+ cyc of HBM latency per step.
// Only the LDS h ping-pong needs barrier ordering: ds_write -> lgkmcnt(0) ->
// s_barrier -> ds_read. x loads are thread-private (compiler inserts counted
// vmcnt at use); h_out stores have no in-kernel reader. sched_barrier(0) fences
// keep hipcc from moving LDS ops across the barrier (rule #18).

#define SCAN_STEP(XREG, TPRE)                                                   \
    do {                                                                        \
        f16x2 xlo = __builtin_bit_cast(f16x2, XREG.x);                          \
        f16x2 xhi = __builtin_bit_cast(f16x2, XREG.y);                          \
        XREG = *(const uint2*)(xg + (long)(TPRE)*2048);                         \
        const uint4* hh4 = (const uint4*)(hq[cur] + kg*64);                     \
        int S0 = 0, S1 = 0, S2 = 0, S3 = 0;                                     \
        _Pragma("unroll")                                                       \
        for (int c = 0; c < 4; ++c) {                                           \
            uint4 hh = hh4[c];                                                  \
            uint4 r0 = Rr[0][c], r1 = Rr[1][c], r2 = Rr[2][c], r3 = Rr[3][c];   \
            S0 = dot4i(r0.x, hh.x, S0); S0 = dot4i(r0.y, hh.y, S0);             \
            S0 = dot4i(r0.z, hh.z, S0); S0 = dot4i(r0.w, hh.w, S0);             \
            S1 = dot4i(r1.x, hh.x, S1); S1 = dot4i(r1.y, hh.y, S1);             \
            S1 = dot4i(r1.z, hh.z, S1); S1 = dot4i(r1.w, hh.w, S1);             \
            S2 = dot4i(r2.x, hh.x, S2); S2 = dot4i(r2.y, hh.y, S2);             \
            S2 = dot4i(r2.z, hh.z, S2); S2 = dot4i(r2.w, hh.w, S2);             \
            S3 = dot4i(r3.x, hh.x, S3); S3 = dot4i(r3.y, hh.y, S3);             \
            S3 = dot4i(r3.z, hh.z, S3); S3 = dot4i(r3.w, hh.w, S3);             \
        }                                                                       \
        S0 = quad_red(S0); S1 = quad_red(S1);                                   \
        S2 = quad_red(S2); S3 = quad_red(S3);                                   \
        float pz = rs[0]*(float)S0 + (float)xlo[0];                             \
        float pi = rs[1]*(float)S1 + (float)xlo[1];                             \
        float pf = rs[2]*(float)S2 + (float)xhi[0];                             \
        float po = rs[3]*(float)S3 + (float)xhi[1];                             \
        float e = __expf(-2.0f * fabsf(pz));                                    \
        float z = copysignf((1.0f - e) / (1.0f + e), pz);                       \
        float o = 1.0f / (1.0f + __expf(-po));                                  \
        float mn = fmaxf(pf + mst, pi);                                         \
        float ig = __expf(pi - mn);                                             \
        float fg = __expf(pf + mst - mn);                                       \
        cst = fg*cst + ig*z;                                                    \
        nst = fg*nst + ig;                                                      \
        mst = mn;                                                               \
        float h = o * (cst / nst);                                              \
        if (kg == 0) {                                                          \
            hq[cur^1][gb] = (char)(int)rintf(h * 127.f);                        \
            hrow[gb] = __float2bfloat16(h);                                     \
        }                                                                       \
        __builtin_amdgcn_sched_barrier(0);                                      \
        asm volatile("s_waitcnt lgkmcnt(0)" ::: "memory");                      \
        __builtin_amdgcn_s_barrier();                                           \
        __builtin_amdgcn_sched_barrier(0);                                      \
        cur ^= 1;                                                               \
        hrow += HDIM;                                                           \
    } while (0)

__global__ __launch_bounds__(1024) __attribute__((amdgpu_waves_per_eu(4, 4)))
void k_scan(const f16* __restrict__ xW, const char* __restrict__ R8,
            const float* __restrict__ rscale, bf16* __restrict__ h_out)
{
    __shared__ char hq[2][256];                      // i8 h, ping-pong
    const int tid = threadIdx.x;
    const int b   = blockIdx.x;
    const int kg  = tid & 3;                         // k-slice [kg*64, kg*64+64)
    const int gb  = tid >> 2;                        // row j in [0,256)

    // one-time: R8 rows g = gb + 256m, k-slice kg -> 16 uint4 in VGPRs
    uint4 Rr[4][4];
    float rs[4];
    #pragma unroll
    for (int m = 0; m < 4; ++m) {
        const uint4* rp = (const uint4*)(R8 + (long)(gb + 256*m)*256 + kg*64);
        #pragma unroll
        for (int c = 0; c < 4; ++c) Rr[m][c] = rp[c];
        rs[m] = rscale[gb + 256*m] * (1.0f/127.0f);  // fold h dequant scale
    }
    if (tid < 64) ((unsigned*)hq[0])[tid] = 0u;

    // gate-interleaved x rows; loads for t >= TT read <=4KB past this batch's
    // slice (still inside d_ws: next batch / h region), values never consumed.
    const char* xg = (const char*)xW + (long)b * TT * 2048 + gb*8;
    bf16* hrow = h_out + (long)b * TT * HDIM;

    uint2 XA = *(const uint2*)(xg);                  // t = 0
    uint2 XB = *(const uint2*)(xg + 2048);           // t = 1
    float cst = 0.f, nst = 0.f, mst = 0.f;
    int cur = 0;
    __syncthreads();

    for (int t = 0; t < TT; t += 2) {
        SCAN_STEP(XA, t + 2);
        SCAN_STEP(XB, t + 3);
    }
}

// ---------------- launch ----------------
extern "C" void kernel_launch(void* const* d_in, const int* in_sizes, int n_in,
                              void* d_out, int out_size, void* d_ws, size_t ws_size,
                              hipStream_t stream) {
    const float* x     = (const float*)d_in[0];
    const float* ln1w  = (const float*)d_in[1];
    const float* ln1b  = (const float*)d_in[2];
    const float* W     = (const float*)d_in[3];
    const float* R     = (const float*)d_in[4];
    const float* bg    = (const float*)d_in[5];
    const float* upW   = (const float*)d_in[6];
    const float* upb   = (const float*)d_in[7];
    const float* gateW = (const float*)d_in[8];
    const float* gateb = (const float*)d_in[9];
    const float* downW = (const float*)d_in[10];
    const float* downb = (const float*)d_in[11];
    const float* ln2w  = (const float*)d_in[12];
    const float* ln2b  = (const float*)d_in[13];

    char* ws = (char*)d_ws;
    size_t off = 0;
    auto alloc = [&](size_t bytes) { char* p = ws + off; off += (bytes + 255) & ~255ULL; return p; };
    f16*  mlp16   = (f16*)alloc((size_t)NTOK*HDIM*2);     // holds nx first, then mlp (disjoint lifetimes)
    char* regionB = alloc((size_t)NTOK*G4*2);             // xW, then gate_out+prod
    bf16* h       = (bf16*)alloc((size_t)NTOK*HDIM*2);
    bf16* Wb      = (bf16*)alloc(262144*2);
    char* R8      = (char*)alloc(262144);
    float* rscale = (float*)alloc(1024*4);
    bf16* gWb     = (bf16*)alloc((size_t)MPAD*256*2);
    bf16* uWb     = (bf16*)alloc((size_t)MPAD*256*2);
    bf16* dWb     = (bf16*)alloc((size_t)256*MPAD*2);
    float* gbp    = (float*)alloc(MPAD*4);
    float* ubp    = (float*)alloc(MPAD*4);

    bf16* nx       = (bf16*)mlp16;                        // phase 1 use of that region
    f16*  xWb      = (f16*)regionB;                       // 131072 x 1024 f16 (gate-interleaved)
    f16*  gate_out = (f16*)regionB;                       // reuse after scan: 131072 x 384 f16
    bf16* prod     = (bf16*)(regionB + (size_t)NTOK*MPAD*2);

    k_prep_w   <<<1024, 256, 0, stream>>>(W, Wb);
    k_prep_r8  <<<256, 256, 0, stream>>>(R, R8, rscale);
    k_prep_gu  <<<384, 256, 0, stream>>>(gateW, upW, gateb, upb, gWb, uWb, gbp, ubp);
    k_prep_down<<<384, 256, 0, stream>>>(downW, dWb);
    k_ln1      <<<NTOK/4, 256, 0, stream>>>(x, ln1w, ln1b, nx);
    // xW = nx @ W^T + b   (f16, gate-interleaved per token)
    k_gemm<MODE_XW_F16><<<dim3(1024, 16), 256, 0, stream>>>(nx, Wb, bg, xWb, nullptr, 256, 256, 256, 1024, 0);
    // sequential sLSTM scan
    k_scan     <<<64, 1024, 0, stream>>>(xWb, R8, rscale, h);
    // gate = gelu(h @ gateW^T + gate_b)  (f16)
    k_gemm<MODE_GELU_F16><<<dim3(1024, 6), 256, 0, stream>>>(h, gWb, gbp, gate_out, nullptr, 256, 256, 256, MPAD, 0);
    // prod = gate * (h @ upW^T + up_b)   (bf16, padded cols auto-zero)
    k_gemm<MODE_MUL_BF16><<<dim3(1024, 6), 256, 0, stream>>>(h, uWb, ubp, prod, gate_out, 256, 256, 256, MPAD, MPAD);
    // mlp = prod @ downW^T + down_b      (f16 out, K=384)
    k_gemm<MODE_F16><<<dim3(1024, 4), 256, 0, stream>>>(prod, dWb, downb, mlp16, nullptr, MPAD, MPAD, MPAD, HDIM, 0);
    // out = LN(mlp) + x
    k_ln2      <<<NTOK/4, 256, 0, stream>>>(mlp16, x, ln2w, ln2b, (float*)d_out);
}

// Round 8
// 2738.971 us; speedup vs baseline: 1.8006x; 1.1192x over previous
//
#include <hip/hip_runtime.h>
#include <hip/hip_bf16.h>
#include <hip/hip_fp16.h>

typedef _Float16 f16;
typedef __hip_bfloat16 bf16;
typedef short bf16x8 __attribute__((ext_vector_type(8)));
typedef float f32x4 __attribute__((ext_vector_type(4)));
typedef int i32x4 __attribute__((ext_vector_type(4)));
typedef _Float16 f16x2 __attribute__((ext_vector_type(2)));

#define HDIM 256
#define G4   1024
#define TT   2048
#define NB   64
#define NTOK (64*2048)
#define MPAD 384   // 341 padded to 384 (6 x 64)

// ---------------- helpers ----------------
__device__ __forceinline__ float gelu_tanh(float x) {
    // jax.nn.gelu default (approximate=True)
    float x3 = x*x*x;
    float t = tanhf(0.7978845608028654f * (x + 0.044715f * x3));
    return 0.5f * x * (1.0f + t);
}

// ---------------- prep: dtype conversion + padding ----------------
__global__ void k_prep_w(const float* __restrict__ W, bf16* __restrict__ Wb) {
    int i = blockIdx.x*256 + threadIdx.x;          // 262144 total
    Wb[i] = __float2bfloat16(W[i]);
}

// R -> int8 with per-gate-row scale. One wave per row (256 f32 -> 256 i8).
__global__ __launch_bounds__(256) void k_prep_r8(const float* __restrict__ R,
        char* __restrict__ R8, float* __restrict__ rscale) {
    int wave = threadIdx.x >> 6, lane = threadIdx.x & 63;
    int g = blockIdx.x*4 + wave;
    float4 v = ((const float4*)(R + (long)g*256))[lane];
    float mx = fmaxf(fmaxf(fabsf(v.x), fabsf(v.y)), fmaxf(fabsf(v.z), fabsf(v.w)));
    #pragma unroll
    for (int m = 1; m < 64; m <<= 1) mx = fmaxf(mx, __shfl_xor(mx, m, 64));
    float inv = (mx > 0.f) ? 127.f/mx : 0.f;
    int q0 = (int)rintf(v.x*inv), q1 = (int)rintf(v.y*inv);
    int q2 = (int)rintf(v.z*inv), q3 = (int)rintf(v.w*inv);
    unsigned packed = (q0 & 0xff) | ((q1 & 0xff) << 8) | ((q2 & 0xff) << 16) | ((q3 & 0xff) << 24);
    ((unsigned*)(R8 + (long)g*256))[lane] = packed;
    if (lane == 0) rscale[g] = mx * (1.0f/127.f);
}

__global__ void k_prep_gu(const float* __restrict__ gW, const float* __restrict__ uW,
                          const float* __restrict__ gb, const float* __restrict__ ub,
                          bf16* __restrict__ gWb, bf16* __restrict__ uWb,
                          float* __restrict__ gbp, float* __restrict__ ubp) {
    int i = blockIdx.x*256 + threadIdx.x;          // 384*256 total
    int r = i >> 8, c = i & 255;
    gWb[i] = __float2bfloat16(r < 341 ? gW[r*256 + c] : 0.f);
    uWb[i] = __float2bfloat16(r < 341 ? uW[r*256 + c] : 0.f);
    if (i < 384) {
        gbp[i] = i < 341 ? gb[i] : 0.f;
        ubp[i] = i < 341 ? ub[i] : 0.f;
    }
}

__global__ void k_prep_down(const float* __restrict__ dW, bf16* __restrict__ dWb) {
    int i = blockIdx.x*256 + threadIdx.x;          // 256*384 total
    int r = i / 384, c = i % 384;
    dWb[i] = __float2bfloat16(c < 341 ? dW[r*341 + c] : 0.f);
}

// ---------------- LayerNorm 1: f32 -> bf16 ----------------
__global__ __launch_bounds__(256) void k_ln1(const float* __restrict__ x,
        const float* __restrict__ w, const float* __restrict__ b,
        bf16* __restrict__ nx) {
    int wave = threadIdx.x >> 6, lane = threadIdx.x & 63;
    long tok = (long)blockIdx.x * 4 + wave;
    float4 v = ((const float4*)(x + tok*HDIM))[lane];
    float s = v.x + v.y + v.z + v.w;
    float q = v.x*v.x + v.y*v.y + v.z*v.z + v.w*v.w;
    #pragma unroll
    for (int m = 1; m < 64; m <<= 1) { s += __shfl_xor(s, m, 64); q += __shfl_xor(q, m, 64); }
    float mean = s * (1.0f/HDIM);
    float rs = rsqrtf(q*(1.0f/HDIM) - mean*mean + 1e-5f);
    float4 wv = ((const float4*)w)[lane];
    float4 bv = ((const float4*)b)[lane];
    bf16 tmp[4];
    tmp[0] = __float2bfloat16((v.x-mean)*rs*wv.x + bv.x);
    tmp[1] = __float2bfloat16((v.y-mean)*rs*wv.y + bv.y);
    tmp[2] = __float2bfloat16((v.z-mean)*rs*wv.z + bv.z);
    tmp[3] = __float2bfloat16((v.w-mean)*rs*wv.w + bv.w);
    *(ushort4*)(nx + tok*HDIM + lane*4) = *(ushort4*)tmp;
}

// ---------------- LayerNorm 2 + residual: f16 mlp + f32 x -> f32 out ----------------
__global__ __launch_bounds__(256) void k_ln2(const f16* __restrict__ mlp,
        const float* __restrict__ x, const float* __restrict__ w,
        const float* __restrict__ b, float* __restrict__ out) {
    int wave = threadIdx.x >> 6, lane = threadIdx.x & 63;
    long tok = (long)blockIdx.x * 4 + wave;
    const f16* mr = mlp + tok*HDIM + lane*4;
    float4 v; v.x = (float)mr[0]; v.y = (float)mr[1]; v.z = (float)mr[2]; v.w = (float)mr[3];
    float s = v.x + v.y + v.z + v.w;
    float q = v.x*v.x + v.y*v.y + v.z*v.z + v.w*v.w;
    #pragma unroll
    for (int m = 1; m < 64; m <<= 1) { s += __shfl_xor(s, m, 64); q += __shfl_xor(q, m, 64); }
    float mean = s * (1.0f/HDIM);
    float rs = rsqrtf(q*(1.0f/HDIM) - mean*mean + 1e-5f);
    float4 wv = ((const float4*)w)[lane];
    float4 bv = ((const float4*)b)[lane];
    float4 xv = ((const float4*)(x + tok*HDIM))[lane];
    float4 ov;
    ov.x = (v.x-mean)*rs*wv.x + bv.x + xv.x;
    ov.y = (v.y-mean)*rs*wv.y + bv.y + xv.y;
    ov.z = (v.z-mean)*rs*wv.z + bv.z + xv.z;
    ov.w = (v.w-mean)*rs*wv.w + bv.w + xv.w;
    ((float4*)(out + tok*HDIM))[lane] = ov;
}

// ---------------- GEMM: C[M x N] = A[M x K] * B[N x K]^T + bias ----------------
// MODE_XW_F16 writes gate-interleaved layout: [m][n&255][n>>8] (4 f16 per row j).
enum { MODE_F16 = 0, MODE_GELU_F16 = 1, MODE_MUL_BF16 = 2, MODE_XW_F16 = 3 };

template<int MODE>
__global__ __launch_bounds__(256) void k_gemm(
    const bf16* __restrict__ A, const bf16* __restrict__ Bm,
    const float* __restrict__ bias, void* __restrict__ Cv,
    const f16* __restrict__ gatebuf,
    int K, int lda, int ldb, int ldc, int ldg)
{
    // BM=128, BN=64, BK=64; rows stored as 64 bf16 = 128B = 8x16B slots, XOR-swizzled
    __shared__ char Al[128*128];
    __shared__ char Bl[64*128];
    const int tid = threadIdx.x;
    const long bm = (long)blockIdx.x * 128;
    const int bn = blockIdx.y * 64;
    const int wave = tid >> 6, lane = tid & 63;
    const int wm = wave >> 1, wn = wave & 1;        // 2x2 waves, each 64x32
    const int l16 = lane & 15, lq = lane >> 4;
    f32x4 acc[4][2] = {};
    for (int k0 = 0; k0 < K; k0 += 64) {
        #pragma unroll
        for (int p = 0; p < 4; ++p) {               // A: 128 rows x 8 chunks
            int ci = tid + p*256;
            int row = ci >> 3, s = ci & 7;
            uint4 d = *(const uint4*)(A + (bm + row)*lda + k0 + s*8);
            *(uint4*)(Al + row*128 + ((s ^ (row&7))<<4)) = d;
        }
        #pragma unroll
        for (int p = 0; p < 2; ++p) {               // B: 64 rows x 8 chunks
            int ci = tid + p*256;
            int row = ci >> 3, s = ci & 7;
            uint4 d = *(const uint4*)(Bm + (long)(bn + row)*ldb + k0 + s*8);
            *(uint4*)(Bl + row*128 + ((s ^ (row&7))<<4)) = d;
        }
        __syncthreads();
        #pragma unroll
        for (int kc = 0; kc < 2; ++kc) {
            bf16x8 bf[2];
            #pragma unroll
            for (int fn = 0; fn < 2; ++fn) {
                int row = wn*32 + fn*16 + l16;
                int slot = (kc<<2) + lq;
                bf[fn] = *(const bf16x8*)(Bl + row*128 + ((slot ^ (row&7))<<4));
            }
            #pragma unroll
            for (int fm = 0; fm < 4; ++fm) {
                int row = wm*64 + fm*16 + l16;
                int slot = (kc<<2) + lq;
                bf16x8 af = *(const bf16x8*)(Al + row*128 + ((slot ^ (row&7))<<4));
                acc[fm][0] = __builtin_amdgcn_mfma_f32_16x16x32_bf16(af, bf[0], acc[fm][0], 0,0,0);
                acc[fm][1] = __builtin_amdgcn_mfma_f32_16x16x32_bf16(af, bf[1], acc[fm][1], 0,0,0);
            }
        }
        __syncthreads();
    }
    #pragma unroll
    for (int fm = 0; fm < 4; ++fm) {
        #pragma unroll
        for (int fn = 0; fn < 2; ++fn) {
            int n = bn + wn*32 + fn*16 + l16;
            float bv = bias[n];
            #pragma unroll
            for (int r = 0; r < 4; ++r) {
                long m = bm + wm*64 + fm*16 + lq*4 + r;
                float v = acc[fm][fn][r] + bv;
                if constexpr (MODE == MODE_F16) {
                    ((f16*)Cv)[m*ldc + n] = (f16)v;
                } else if constexpr (MODE == MODE_XW_F16) {
                    ((f16*)Cv)[m*ldc + ((n & 255) << 2) + (n >> 8)] = (f16)v;
                } else if constexpr (MODE == MODE_GELU_F16) {
                    ((f16*)Cv)[m*ldc + n] = (f16)gelu_tanh(v);
                } else {
                    float g = (float)gatebuf[m*ldg + n];
                    ((bf16*)Cv)[m*ldc + n] = __float2bfloat16(g * v);
                }
            }
        }
    }
}

// ---------------- sLSTM scan: 64 blocks (1 batch each), 512 threads / 8 waves ----
// MFMA path: per step, pre = R8[1024x256] x h8[256] on the i8 matrix pipe.
// v_mfma_i32_16x16x64_i8 with A = h broadcast (all 16 M-rows = same h k-slice):
// D[r][c] = pre[gate g0+c] for every r -> built-in 16x replication, epilogue reads
// reg 0. Wave w owns j-block [w*32, w*32+32): 8 gate-tiles (2 j-halves x 4 gates)
// x 4 k-mfma = 32 mfma/wave/step. B-frags (R8) live in 128 VGPRs, loaded once.
// A-frags: 4 broadcast ds_read_b128 from the 256B h ping-pong buffer (16 lanes
// per address, banks disjoint -> conflict-free). Lane l&15 = j-column; every lane
// computes the epilogue for its 2 j's (4 replicas across l>>4); l>>4==0 publishes.
// Raw s_barrier + lgkmcnt(0) per step (no vmcnt drain); sched_barrier fences.
// Fragment k-mapping assumed: lane l, reg r, byte b -> k = (l>>4)*16 + r*4 + b.

__global__ __launch_bounds__(512) __attribute__((amdgpu_waves_per_eu(2, 2)))
void k_scan(const f16* __restrict__ xW, const char* __restrict__ R8,
            const float* __restrict__ rscale, bf16* __restrict__ h_out)
{
    __shared__ char hq[2][256];                      // i8 h, ping-pong
    const int tid = threadIdx.x;
    const int b    = blockIdx.x;
    const int w    = tid >> 6;                       // wave 0..7
    const int lane = tid & 63;
    const int c    = lane & 15;                      // j-column / gate-column
    const int q    = lane >> 4;                      // k lane-group (0..3)
    const int j0   = w*32 + c;
    const int j1   = j0 + 16;

    // ---- one-time: B-fragments (R8) -> 32 uint4 = 128 VGPRs ----
    // Bf[half][m][kk]: lane holds R8[g = w*32 + half*16 + c + 256m][kk*64 + q*16 .. +16)
    uint4 Bf0[4][4], Bf1[4][4];
    #pragma unroll
    for (int m = 0; m < 4; ++m) {
        #pragma unroll
        for (int kk = 0; kk < 4; ++kk) {
            Bf0[m][kk] = *(const uint4*)(R8 + (long)(j0 + 256*m)*256 + kk*64 + q*16);
            Bf1[m][kk] = *(const uint4*)(R8 + (long)(j1 + 256*m)*256 + kk*64 + q*16);
        }
    }
    float rs0[4], rs1[4];
    #pragma unroll
    for (int m = 0; m < 4; ++m) {
        rs0[m] = rscale[j0 + 256*m] * (1.0f/127.0f);
        rs1[m] = rscale[j1 + 256*m] * (1.0f/127.0f);
    }
    if (tid < 64) ((unsigned*)hq[0])[tid] = 0u;

    // gate-interleaved x rows; per-lane 8B for each of its two j's.
    const char* xg = (const char*)xW + (long)b * TT * 2048;
    bf16* hrow = h_out + (long)b * TT * HDIM;

    uint2 XA0 = *(const uint2*)(xg + j0*8);          // t=0
    uint2 XA1 = *(const uint2*)(xg + j1*8);
    uint2 XB0 = *(const uint2*)(xg + 2048 + j0*8);   // t=1
    uint2 XB1 = *(const uint2*)(xg + 2048 + j1*8);
    float cst0 = 0.f, nst0 = 0.f, mst0 = 0.f;
    float cst1 = 0.f, nst1 = 0.f, mst1 = 0.f;
    int cur = 0;
    __syncthreads();

#define SLSTM_EPI(PZ, PI, PF, PO, CST, NST, MST, HOUT)                          \
    do {                                                                        \
        float e = __expf(-2.0f * fabsf(PZ));                                    \
        float z = copysignf((1.0f - e) / (1.0f + e), PZ);                       \
        float o = 1.0f / (1.0f + __expf(-(PO)));                                \
        float mn = fmaxf((PF) + MST, PI);                                       \
        float ig = __expf((PI) - mn);                                           \
        float fg = __expf((PF) + MST - mn);                                     \
        CST = fg*CST + ig*z;                                                    \
        NST = fg*NST + ig;                                                      \
        MST = mn;                                                               \
        HOUT = o * (CST / NST);                                                 \
    } while (0)

#define SCAN_STEP(X0, X1, TPRE)                                                 \
    do {                                                                        \
        f16x2 x0lo = __builtin_bit_cast(f16x2, X0.x);                           \
        f16x2 x0hi = __builtin_bit_cast(f16x2, X0.y);                           \
        f16x2 x1lo = __builtin_bit_cast(f16x2, X1.x);                           \
        f16x2 x1hi = __builtin_bit_cast(f16x2, X1.y);                           \
        X0 = *(const uint2*)(xg + (long)(TPRE)*2048 + j0*8);                    \
        X1 = *(const uint2*)(xg + (long)(TPRE)*2048 + j1*8);                    \
        i32x4 af[4];                                                            \
        _Pragma("unroll")                                                       \
        for (int kk = 0; kk < 4; ++kk)                                          \
            af[kk] = __builtin_bit_cast(i32x4,                                  \
                         *(const uint4*)(hq[cur] + kk*64 + q*16));              \
        i32x4 ac00 = {0,0,0,0}, ac01 = {0,0,0,0}, ac02 = {0,0,0,0}, ac03 = {0,0,0,0}; \
        i32x4 ac10 = {0,0,0,0}, ac11 = {0,0,0,0}, ac12 = {0,0,0,0}, ac13 = {0,0,0,0}; \
        _Pragma("unroll")                                                       \
        for (int kk = 0; kk < 4; ++kk) {                                        \
            ac00 = __builtin_amdgcn_mfma_i32_16x16x64_i8(af[kk], __builtin_bit_cast(i32x4, Bf0[0][kk]), ac00, 0,0,0); \
            ac01 = __builtin_amdgcn_mfma_i32_16x16x64_i8(af[kk], __builtin_bit_cast(i32x4, Bf0[1][kk]), ac01, 0,0,0); \
            ac02 = __builtin_amdgcn_mfma_i32_16x16x64_i8(af[kk], __builtin_bit_cast(i32x4, Bf0[2][kk]), ac02, 0,0,0); \
            ac03 = __builtin_amdgcn_mfma_i32_16x16x64_i8(af[kk], __builtin_bit_cast(i32x4, Bf0[3][kk]), ac03, 0,0,0); \
            ac10 = __builtin_amdgcn_mfma_i32_16x16x64_i8(af[kk], __builtin_bit_cast(i32x4, Bf1[0][kk]), ac10, 0,0,0); \
            ac11 = __builtin_amdgcn_mfma_i32_16x16x64_i8(af[kk], __builtin_bit_cast(i32x4, Bf1[1][kk]), ac11, 0,0,0); \
            ac12 = __builtin_amdgcn_mfma_i32_16x16x64_i8(af[kk], __builtin_bit_cast(i32x4, Bf1[2][kk]), ac12, 0,0,0); \
            ac13 = __builtin_amdgcn_mfma_i32_16x16x64_i8(af[kk], __builtin_bit_cast(i32x4, Bf1[3][kk]), ac13, 0,0,0); \
        }                                                                       \
        float pz0 = rs0[0]*(float)ac00[0] + (float)x0lo[0];                     \
        float pi0 = rs0[1]*(float)ac01[0] + (float)x0lo[1];                     \
        float pf0 = rs0[2]*(float)ac02[0] + (float)x0hi[0];                     \
        float po0 = rs0[3]*(float)ac03[0] + (float)x0hi[1];                     \
        float pz1 = rs1[0]*(float)ac10[0] + (float)x1lo[0];                     \
        float pi1 = rs1[1]*(float)ac11[0] + (float)x1lo[1];                     \
        float pf1 = rs1[2]*(float)ac12[0] + (float)x1hi[0];                     \
        float po1 = rs1[3]*(float)ac13[0] + (float)x1hi[1];                     \
        float h0, h1;                                                           \
        SLSTM_EPI(pz0, pi0, pf0, po0, cst0, nst0, mst0, h0);                    \
        SLSTM_EPI(pz1, pi1, pf1, po1, cst1, nst1, mst1, h1);                    \
        if (q == 0) {                                                           \
            hq[cur^1][j0] = (char)(int)rintf(h0 * 127.f);                       \
            hq[cur^1][j1] = (char)(int)rintf(h1 * 127.f);                       \
            hrow[j0] = __float2bfloat16(h0);                                    \
            hrow[j1] = __float2bfloat16(h1);                                    \
        }                                                                       \
        __builtin_amdgcn_sched_barrier(0);                                      \
        asm volatile("s_waitcnt lgkmcnt(0)" ::: "memory");                      \
        __builtin_amdgcn_s_barrier();                                           \
        __builtin_amdgcn_sched_barrier(0);                                      \
        cur ^= 1;                                                               \
        hrow += HDIM;                                                           \
    } while (0)

    for (int t = 0; t < TT; t += 2) {
        SCAN_STEP(XA0, XA1, t + 2);
        SCAN_STEP(XB0, XB1, t + 3);
    }
#undef SCAN_STEP
#undef SLSTM_EPI
}

// ---------------- launch ----------------
extern "C" void kernel_launch(void* const* d_in, const int* in_sizes, int n_in,
                              void* d_out, int out_size, void* d_ws, size_t ws_size,
                              hipStream_t stream) {
    const float* x     = (const float*)d_in[0];
    const float* ln1w  = (const float*)d_in[1];
    const float* ln1b  = (const float*)d_in[2];
    const float* W     = (const float*)d_in[3];
    const float* R     = (const float*)d_in[4];
    const float* bg    = (const float*)d_in[5];
    const float* upW   = (const float*)d_in[6];
    const float* upb   = (const float*)d_in[7];
    const float* gateW = (const float*)d_in[8];
    const float* gateb = (const float*)d_in[9];
    const float* downW = (const float*)d_in[10];
    const float* downb = (const float*)d_in[11];
    const float* ln2w  = (const float*)d_in[12];
    const float* ln2b  = (const float*)d_in[13];

    char* ws = (char*)d_ws;
    size_t off = 0;
    auto alloc = [&](size_t bytes) { char* p = ws + off; off += (bytes + 255) & ~255ULL; return p; };
    f16*  mlp16   = (f16*)alloc((size_t)NTOK*HDIM*2);     // holds nx first, then mlp (disjoint lifetimes)
    char* regionB = alloc((size_t)NTOK*G4*2);             // xW, then gate_out+prod
    bf16* h       = (bf16*)alloc((size_t)NTOK*HDIM*2);
    bf16* Wb      = (bf16*)alloc(262144*2);
    char* R8      = (char*)alloc(262144);
    float* rscale = (float*)alloc(1024*4);
    bf16* gWb     = (bf16*)alloc((size_t)MPAD*256*2);
    bf16* uWb     = (bf16*)alloc((size_t)MPAD*256*2);
    bf16* dWb     = (bf16*)alloc((size_t)256*MPAD*2);
    float* gbp    = (float*)alloc(MPAD*4);
    float* ubp    = (float*)alloc(MPAD*4);

    bf16* nx       = (bf16*)mlp16;                        // phase 1 use of that region
    f16*  xWb      = (f16*)regionB;                       // 131072 x 1024 f16 (gate-interleaved)
    f16*  gate_out = (f16*)regionB;                       // reuse after scan: 131072 x 384 f16
    bf16* prod     = (bf16*)(regionB + (size_t)NTOK*MPAD*2);

    k_prep_w   <<<1024, 256, 0, stream>>>(W, Wb);
    k_prep_r8  <<<256, 256, 0, stream>>>(R, R8, rscale);
    k_prep_gu  <<<384, 256, 0, stream>>>(gateW, upW, gateb, upb, gWb, uWb, gbp, ubp);
    k_prep_down<<<384, 256, 0, stream>>>(downW, dWb);
    k_ln1      <<<NTOK/4, 256, 0, stream>>>(x, ln1w, ln1b, nx);
    // xW = nx @ W^T + b   (f16, gate-interleaved per token)
    k_gemm<MODE_XW_F16><<<dim3(1024, 16), 256, 0, stream>>>(nx, Wb, bg, xWb, nullptr, 256, 256, 256, 1024, 0);
    // sequential sLSTM scan (MFMA i8)
    k_scan     <<<64, 512, 0, stream>>>(xWb, R8, rscale, h);
    // gate = gelu(h @ gateW^T + gate_b)  (f16)
    k_gemm<MODE_GELU_F16><<<dim3(1024, 6), 256, 0, stream>>>(h, gWb, gbp, gate_out, nullptr, 256, 256, 256, MPAD, 0);
    // prod = gate * (h @ upW^T + up_b)   (bf16, padded cols auto-zero)
    k_gemm<MODE_MUL_BF16><<<dim3(1024, 6), 256, 0, stream>>>(h, uWb, ubp, prod, gate_out, 256, 256, 256, MPAD, MPAD);
    // mlp = prod @ downW^T + down_b      (f16 out, K=384)
    k_gemm<MODE_F16><<<dim3(1024, 4), 256, 0, stream>>>(prod, dWb, downb, mlp16, nullptr, MPAD, MPAD, MPAD, HDIM, 0);
    // out = LN(mlp) + x
    k_ln2      <<<NTOK/4, 256, 0, stream>>>(mlp16, x, ln2w, ln2b, (float*)d_out);
}

// Round 9
// 2567.485 us; speedup vs baseline: 1.9209x; 1.0668x over previous
//
#include <hip/hip_runtime.h>
#include <hip/hip_bf16.h>
#include <hip/hip_fp16.h>

typedef _Float16 f16;
typedef __hip_bfloat16 bf16;
typedef short bf16x8 __attribute__((ext_vector_type(8)));
typedef float f32x4 __attribute__((ext_vector_type(4)));
typedef int i32x4 __attribute__((ext_vector_type(4)));
typedef _Float16 f16x2 __attribute__((ext_vector_type(2)));

#define HDIM 256
#define G4   1024
#define TT   2048
#define NB   64
#define NTOK (64*2048)
#define MPAD 384   // 341 padded to 384 (6 x 64)

// ---------------- helpers ----------------
__device__ __forceinline__ float gelu_tanh(float x) {
    // jax.nn.gelu default (approximate=True)
    float x3 = x*x*x;
    float t = tanhf(0.7978845608028654f * (x + 0.044715f * x3));
    return 0.5f * x * (1.0f + t);
}

// ---------------- prep: dtype conversion + padding ----------------
__global__ void k_prep_w(const float* __restrict__ W, bf16* __restrict__ Wb) {
    int i = blockIdx.x*256 + threadIdx.x;          // 262144 total
    Wb[i] = __float2bfloat16(W[i]);
}

// R -> int8 with per-gate-row scale. One wave per row (256 f32 -> 256 i8).
__global__ __launch_bounds__(256) void k_prep_r8(const float* __restrict__ R,
        char* __restrict__ R8, float* __restrict__ rscale) {
    int wave = threadIdx.x >> 6, lane = threadIdx.x & 63;
    int g = blockIdx.x*4 + wave;
    float4 v = ((const float4*)(R + (long)g*256))[lane];
    float mx = fmaxf(fmaxf(fabsf(v.x), fabsf(v.y)), fmaxf(fabsf(v.z), fabsf(v.w)));
    #pragma unroll
    for (int m = 1; m < 64; m <<= 1) mx = fmaxf(mx, __shfl_xor(mx, m, 64));
    float inv = (mx > 0.f) ? 127.f/mx : 0.f;
    int q0 = (int)rintf(v.x*inv), q1 = (int)rintf(v.y*inv);
    int q2 = (int)rintf(v.z*inv), q3 = (int)rintf(v.w*inv);
    unsigned packed = (q0 & 0xff) | ((q1 & 0xff) << 8) | ((q2 & 0xff) << 16) | ((q3 & 0xff) << 24);
    ((unsigned*)(R8 + (long)g*256))[lane] = packed;
    if (lane == 0) rscale[g] = mx * (1.0f/127.f);
}

__global__ void k_prep_gu(const float* __restrict__ gW, const float* __restrict__ uW,
                          const float* __restrict__ gb, const float* __restrict__ ub,
                          bf16* __restrict__ gWb, bf16* __restrict__ uWb,
                          float* __restrict__ gbp, float* __restrict__ ubp) {
    int i = blockIdx.x*256 + threadIdx.x;          // 384*256 total
    int r = i >> 8, c = i & 255;
    gWb[i] = __float2bfloat16(r < 341 ? gW[r*256 + c] : 0.f);
    uWb[i] = __float2bfloat16(r < 341 ? uW[r*256 + c] : 0.f);
    if (i < 384) {
        gbp[i] = i < 341 ? gb[i] : 0.f;
        ubp[i] = i < 341 ? ub[i] : 0.f;
    }
}

__global__ void k_prep_down(const float* __restrict__ dW, bf16* __restrict__ dWb) {
    int i = blockIdx.x*256 + threadIdx.x;          // 256*384 total
    int r = i / 384, c = i % 384;
    dWb[i] = __float2bfloat16(c < 341 ? dW[r*341 + c] : 0.f);
}

// ---------------- LayerNorm 1: f32 -> bf16 ----------------
__global__ __launch_bounds__(256) void k_ln1(const float* __restrict__ x,
        const float* __restrict__ w, const float* __restrict__ b,
        bf16* __restrict__ nx) {
    int wave = threadIdx.x >> 6, lane = threadIdx.x & 63;
    long tok = (long)blockIdx.x * 4 + wave;
    float4 v = ((const float4*)(x + tok*HDIM))[lane];
    float s = v.x + v.y + v.z + v.w;
    float q = v.x*v.x + v.y*v.y + v.z*v.z + v.w*v.w;
    #pragma unroll
    for (int m = 1; m < 64; m <<= 1) { s += __shfl_xor(s, m, 64); q += __shfl_xor(q, m, 64); }
    float mean = s * (1.0f/HDIM);
    float rs = rsqrtf(q*(1.0f/HDIM) - mean*mean + 1e-5f);
    float4 wv = ((const float4*)w)[lane];
    float4 bv = ((const float4*)b)[lane];
    bf16 tmp[4];
    tmp[0] = __float2bfloat16((v.x-mean)*rs*wv.x + bv.x);
    tmp[1] = __float2bfloat16((v.y-mean)*rs*wv.y + bv.y);
    tmp[2] = __float2bfloat16((v.z-mean)*rs*wv.z + bv.z);
    tmp[3] = __float2bfloat16((v.w-mean)*rs*wv.w + bv.w);
    *(ushort4*)(nx + tok*HDIM + lane*4) = *(ushort4*)tmp;
}

// ---------------- LayerNorm 2 + residual: f16 mlp + f32 x -> f32 out ----------------
__global__ __launch_bounds__(256) void k_ln2(const f16* __restrict__ mlp,
        const float* __restrict__ x, const float* __restrict__ w,
        const float* __restrict__ b, float* __restrict__ out) {
    int wave = threadIdx.x >> 6, lane = threadIdx.x & 63;
    long tok = (long)blockIdx.x * 4 + wave;
    const f16* mr = mlp + tok*HDIM + lane*4;
    float4 v; v.x = (float)mr[0]; v.y = (float)mr[1]; v.z = (float)mr[2]; v.w = (float)mr[3];
    float s = v.x + v.y + v.z + v.w;
    float q = v.x*v.x + v.y*v.y + v.z*v.z + v.w*v.w;
    #pragma unroll
    for (int m = 1; m < 64; m <<= 1) { s += __shfl_xor(s, m, 64); q += __shfl_xor(q, m, 64); }
    float mean = s * (1.0f/HDIM);
    float rs = rsqrtf(q*(1.0f/HDIM) - mean*mean + 1e-5f);
    float4 wv = ((const float4*)w)[lane];
    float4 bv = ((const float4*)b)[lane];
    float4 xv = ((const float4*)(x + tok*HDIM))[lane];
    float4 ov;
    ov.x = (v.x-mean)*rs*wv.x + bv.x + xv.x;
    ov.y = (v.y-mean)*rs*wv.y + bv.y + xv.y;
    ov.z = (v.z-mean)*rs*wv.z + bv.z + xv.z;
    ov.w = (v.w-mean)*rs*wv.w + bv.w + xv.w;
    ((float4*)(out + tok*HDIM))[lane] = ov;
}

// ---------------- GEMM: C[M x N] = A[M x K] * B[N x K]^T + bias ----------------
// MODE_XW_F16 writes gate-interleaved layout: [m][n&255][n>>8] (4 f16 per row j).
enum { MODE_F16 = 0, MODE_GELU_F16 = 1, MODE_MUL_BF16 = 2, MODE_XW_F16 = 3 };

template<int MODE>
__global__ __launch_bounds__(256) void k_gemm(
    const bf16* __restrict__ A, const bf16* __restrict__ Bm,
    const float* __restrict__ bias, void* __restrict__ Cv,
    const f16* __restrict__ gatebuf,
    int K, int lda, int ldb, int ldc, int ldg)
{
    // BM=128, BN=64, BK=64; rows stored as 64 bf16 = 128B = 8x16B slots, XOR-swizzled
    __shared__ char Al[128*128];
    __shared__ char Bl[64*128];
    const int tid = threadIdx.x;
    const long bm = (long)blockIdx.x * 128;
    const int bn = blockIdx.y * 64;
    const int wave = tid >> 6, lane = tid & 63;
    const int wm = wave >> 1, wn = wave & 1;        // 2x2 waves, each 64x32
    const int l16 = lane & 15, lq = lane >> 4;
    f32x4 acc[4][2] = {};
    for (int k0 = 0; k0 < K; k0 += 64) {
        #pragma unroll
        for (int p = 0; p < 4; ++p) {               // A: 128 rows x 8 chunks
            int ci = tid + p*256;
            int row = ci >> 3, s = ci & 7;
            uint4 d = *(const uint4*)(A + (bm + row)*lda + k0 + s*8);
            *(uint4*)(Al + row*128 + ((s ^ (row&7))<<4)) = d;
        }
        #pragma unroll
        for (int p = 0; p < 2; ++p) {               // B: 64 rows x 8 chunks
            int ci = tid + p*256;
            int row = ci >> 3, s = ci & 7;
            uint4 d = *(const uint4*)(Bm + (long)(bn + row)*ldb + k0 + s*8);
            *(uint4*)(Bl + row*128 + ((s ^ (row&7))<<4)) = d;
        }
        __syncthreads();
        #pragma unroll
        for (int kc = 0; kc < 2; ++kc) {
            bf16x8 bf[2];
            #pragma unroll
            for (int fn = 0; fn < 2; ++fn) {
                int row = wn*32 + fn*16 + l16;
                int slot = (kc<<2) + lq;
                bf[fn] = *(const bf16x8*)(Bl + row*128 + ((slot ^ (row&7))<<4));
            }
            #pragma unroll
            for (int fm = 0; fm < 4; ++fm) {
                int row = wm*64 + fm*16 + l16;
                int slot = (kc<<2) + lq;
                bf16x8 af = *(const bf16x8*)(Al + row*128 + ((slot ^ (row&7))<<4));
                acc[fm][0] = __builtin_amdgcn_mfma_f32_16x16x32_bf16(af, bf[0], acc[fm][0], 0,0,0);
                acc[fm][1] = __builtin_amdgcn_mfma_f32_16x16x32_bf16(af, bf[1], acc[fm][1], 0,0,0);
            }
        }
        __syncthreads();
    }
    #pragma unroll
    for (int fm = 0; fm < 4; ++fm) {
        #pragma unroll
        for (int fn = 0; fn < 2; ++fn) {
            int n = bn + wn*32 + fn*16 + l16;
            float bv = bias[n];
            #pragma unroll
            for (int r = 0; r < 4; ++r) {
                long m = bm + wm*64 + fm*16 + lq*4 + r;
                float v = acc[fm][fn][r] + bv;
                if constexpr (MODE == MODE_F16) {
                    ((f16*)Cv)[m*ldc + n] = (f16)v;
                } else if constexpr (MODE == MODE_XW_F16) {
                    ((f16*)Cv)[m*ldc + ((n & 255) << 2) + (n >> 8)] = (f16)v;
                } else if constexpr (MODE == MODE_GELU_F16) {
                    ((f16*)Cv)[m*ldc + n] = (f16)gelu_tanh(v);
                } else {
                    float g = (float)gatebuf[m*ldg + n];
                    ((bf16*)Cv)[m*ldc + n] = __float2bfloat16(g * v);
                }
            }
        }
    }
}

// ---------------- sLSTM scan: 64 blocks (1 batch each), 1024 threads / 16 waves ----
// MFMA i8 path, occupancy-doubled vs R8: 4 waves/SIMD so the per-step serial chain
// (ds_read h -> mfma chain -> dequant -> epilogue -> ds_write -> barrier) of one
// wave hides under the other three. Wave w owns j-block [w*16, w*16+16): 4 gate-
// tiles x 4 k-mfma = 16 mfma/wave/step (64/SIMD/step unchanged vs R8).
// B-frags (R8) in 64 VGPRs; A-frags = 4 broadcast ds_read_b128 of the 256B h
// ping-pong buffer. Lane c=l&15 -> j=w*16+c; q=l>>4 k-group; q==0 publishes.
// Raw s_barrier + lgkmcnt(0) per step; total VGPR ~122 <= 128 (4 waves/SIMD cap).

__global__ __launch_bounds__(1024) __attribute__((amdgpu_waves_per_eu(4, 4)))
void k_scan(const f16* __restrict__ xW, const char* __restrict__ R8,
            const float* __restrict__ rscale, bf16* __restrict__ h_out)
{
    __shared__ char hq[2][256];                      // i8 h, ping-pong
    const int tid = threadIdx.x;
    const int b    = blockIdx.x;
    const int w    = tid >> 6;                       // wave 0..15
    const int lane = tid & 63;
    const int c    = lane & 15;                      // j-column / gate-column
    const int q    = lane >> 4;                      // k lane-group (0..3)
    const int j    = w*16 + c;

    // ---- one-time: B-fragments (R8) -> 16 uint4 = 64 VGPRs ----
    // Bf[m][kk]: lane holds R8[g = j + 256m][kk*64 + q*16 .. +16)
    uint4 Bf[4][4];
    #pragma unroll
    for (int m = 0; m < 4; ++m) {
        #pragma unroll
        for (int kk = 0; kk < 4; ++kk)
            Bf[m][kk] = *(const uint4*)(R8 + (long)(j + 256*m)*256 + kk*64 + q*16);
    }
    float rs[4];
    #pragma unroll
    for (int m = 0; m < 4; ++m)
        rs[m] = rscale[j + 256*m] * (1.0f/127.0f);
    if (tid < 64) ((unsigned*)hq[0])[tid] = 0u;

    // gate-interleaved x rows; per-lane 8B for its j (4 q-replicas, broadcast).
    const char* xg = (const char*)xW + (long)b * TT * 2048 + j*8;
    bf16* hrow = h_out + (long)b * TT * HDIM;

    uint2 XA = *(const uint2*)(xg);                  // t=0
    uint2 XB = *(const uint2*)(xg + 2048);           // t=1
    float cst = 0.f, nst = 0.f, mst = 0.f;
    int cur = 0;
    __syncthreads();

#define SCAN_STEP(XREG, TPRE)                                                   \
    do {                                                                        \
        f16x2 xlo = __builtin_bit_cast(f16x2, XREG.x);                          \
        f16x2 xhi = __builtin_bit_cast(f16x2, XREG.y);                          \
        XREG = *(const uint2*)(xg + (long)(TPRE)*2048);                         \
        i32x4 af[4];                                                            \
        _Pragma("unroll")                                                       \
        for (int kk = 0; kk < 4; ++kk)                                          \
            af[kk] = __builtin_bit_cast(i32x4,                                  \
                         *(const uint4*)(hq[cur] + kk*64 + q*16));              \
        i32x4 ac0 = {0,0,0,0}, ac1 = {0,0,0,0}, ac2 = {0,0,0,0}, ac3 = {0,0,0,0}; \
        _Pragma("unroll")                                                       \
        for (int kk = 0; kk < 4; ++kk) {                                        \
            ac0 = __builtin_amdgcn_mfma_i32_16x16x64_i8(af[kk], __builtin_bit_cast(i32x4, Bf[0][kk]), ac0, 0,0,0); \
            ac1 = __builtin_amdgcn_mfma_i32_16x16x64_i8(af[kk], __builtin_bit_cast(i32x4, Bf[1][kk]), ac1, 0,0,0); \
            ac2 = __builtin_amdgcn_mfma_i32_16x16x64_i8(af[kk], __builtin_bit_cast(i32x4, Bf[2][kk]), ac2, 0,0,0); \
            ac3 = __builtin_amdgcn_mfma_i32_16x16x64_i8(af[kk], __builtin_bit_cast(i32x4, Bf[3][kk]), ac3, 0,0,0); \
        }                                                                       \
        float pz = rs[0]*(float)ac0[0] + (float)xlo[0];                         \
        float pi = rs[1]*(float)ac1[0] + (float)xlo[1];                         \
        float pf = rs[2]*(float)ac2[0] + (float)xhi[0];                         \
        float po = rs[3]*(float)ac3[0] + (float)xhi[1];                         \
        float e = __expf(-2.0f * fabsf(pz));                                    \
        float z = copysignf((1.0f - e) / (1.0f + e), pz);                       \
        float o = 1.0f / (1.0f + __expf(-po));                                  \
        float mn = fmaxf(pf + mst, pi);                                         \
        float ig = __expf(pi - mn);                                             \
        float fg = __expf(pf + mst - mn);                                       \
        cst = fg*cst + ig*z;                                                    \
        nst = fg*nst + ig;                                                      \
        mst = mn;                                                               \
        float h = o * (cst / nst);                                              \
        if (q == 0) {                                                           \
            hq[cur^1][j] = (char)(int)rintf(h * 127.f);                         \
            hrow[j] = __float2bfloat16(h);                                      \
        }                                                                       \
        __builtin_amdgcn_sched_barrier(0);                                      \
        asm volatile("s_waitcnt lgkmcnt(0)" ::: "memory");                      \
        __builtin_amdgcn_s_barrier();                                           \
        __builtin_amdgcn_sched_barrier(0);                                      \
        cur ^= 1;                                                               \
        hrow += HDIM;                                                           \
    } while (0)

    for (int t = 0; t < TT; t += 2) {
        SCAN_STEP(XA, t + 2);
        SCAN_STEP(XB, t + 3);
    }
#undef SCAN_STEP
}

// ---------------- launch ----------------
extern "C" void kernel_launch(void* const* d_in, const int* in_sizes, int n_in,
                              void* d_out, int out_size, void* d_ws, size_t ws_size,
                              hipStream_t stream) {
    const float* x     = (const float*)d_in[0];
    const float* ln1w  = (const float*)d_in[1];
    const float* ln1b  = (const float*)d_in[2];
    const float* W     = (const float*)d_in[3];
    const float* R     = (const float*)d_in[4];
    const float* bg    = (const float*)d_in[5];
    const float* upW   = (const float*)d_in[6];
    const float* upb   = (const float*)d_in[7];
    const float* gateW = (const float*)d_in[8];
    const float* gateb = (const float*)d_in[9];
    const float* downW = (const float*)d_in[10];
    const float* downb = (const float*)d_in[11];
    const float* ln2w  = (const float*)d_in[12];
    const float* ln2b  = (const float*)d_in[13];

    char* ws = (char*)d_ws;
    size_t off = 0;
    auto alloc = [&](size_t bytes) { char* p = ws + off; off += (bytes + 255) & ~255ULL; return p; };
    f16*  mlp16   = (f16*)alloc((size_t)NTOK*HDIM*2);     // holds nx first, then mlp (disjoint lifetimes)
    char* regionB = alloc((size_t)NTOK*G4*2);             // xW, then gate_out+prod
    bf16* h       = (bf16*)alloc((size_t)NTOK*HDIM*2);
    bf16* Wb      = (bf16*)alloc(262144*2);
    char* R8      = (char*)alloc(262144);
    float* rscale = (float*)alloc(1024*4);
    bf16* gWb     = (bf16*)alloc((size_t)MPAD*256*2);
    bf16* uWb     = (bf16*)alloc((size_t)MPAD*256*2);
    bf16* dWb     = (bf16*)alloc((size_t)256*MPAD*2);
    float* gbp    = (float*)alloc(MPAD*4);
    float* ubp    = (float*)alloc(MPAD*4);

    bf16* nx       = (bf16*)mlp16;                        // phase 1 use of that region
    f16*  xWb      = (f16*)regionB;                       // 131072 x 1024 f16 (gate-interleaved)
    f16*  gate_out = (f16*)regionB;                       // reuse after scan: 131072 x 384 f16
    bf16* prod     = (bf16*)(regionB + (size_t)NTOK*MPAD*2);

    k_prep_w   <<<1024, 256, 0, stream>>>(W, Wb);
    k_prep_r8  <<<256, 256, 0, stream>>>(R, R8, rscale);
    k_prep_gu  <<<384, 256, 0, stream>>>(gateW, upW, gateb, upb, gWb, uWb, gbp, ubp);
    k_prep_down<<<384, 256, 0, stream>>>(downW, dWb);
    k_ln1      <<<NTOK/4, 256, 0, stream>>>(x, ln1w, ln1b, nx);
    // xW = nx @ W^T + b   (f16, gate-interleaved per token)
    k_gemm<MODE_XW_F16><<<dim3(1024, 16), 256, 0, stream>>>(nx, Wb, bg, xWb, nullptr, 256, 256, 256, 1024, 0);
    // sequential sLSTM scan (MFMA i8, 16 waves)
    k_scan     <<<64, 1024, 0, stream>>>(xWb, R8, rscale, h);
    // gate = gelu(h @ gateW^T + gate_b)  (f16)
    k_gemm<MODE_GELU_F16><<<dim3(1024, 6), 256, 0, stream>>>(h, gWb, gbp, gate_out, nullptr, 256, 256, 256, MPAD, 0);
    // prod = gate * (h @ upW^T + up_b)   (bf16, padded cols auto-zero)
    k_gemm<MODE_MUL_BF16><<<dim3(1024, 6), 256, 0, stream>>>(h, uWb, ubp, prod, gate_out, 256, 256, 256, MPAD, MPAD);
    // mlp = prod @ downW^T + down_b      (f16 out, K=384)
    k_gemm<MODE_F16><<<dim3(1024, 4), 256, 0, stream>>>(prod, dWb, downb, mlp16, nullptr, MPAD, MPAD, MPAD, HDIM, 0);
    // out = LN(mlp) + x
    k_ln2      <<<NTOK/4, 256, 0, stream>>>(mlp16, x, ln2w, ln2b, (float*)d_out);
}